// Round 3
// baseline (2866.825 us; speedup 1.0000x reference)
//
#include <hip/hip_runtime.h>
#include <hip/hip_bf16.h>

#define SLOTS 5
#define PER 15
#define EGO_DD 32
#define PAIR_DD 10
#define TER_DD 81
#define DX 198
#define ZDIM 332
#define NTOK (64*2048)
#define NEGB (-3.402823466e38f)

struct P {
  const float *x,*w_ego,*b_ego,*w_pair,*b_pair,*w_ter,*b_ter,*w_invtok,*b_invtok,
    *ln1_s,*ln1_b,*wq,*bq,*wk,*bk,*wv,*bv,*wo,*bo,*ln2_s,*ln2_b,*w1,*b1,*w2,*b2,
    *sp_ln_s,*sp_ln_b,*sp_w,*sp_b,*sp_lt,*ap_wq,*ap_bq,*ap_wk,*ap_bk,*ap_we,*ap_be,
    *flat_w,*flat_b,*vr_wego,*vr_bego,*vr_ln_s,*vr_ln_b,*vr_wh,*vr_bh,*vr_wl,*vr_bl,
    *z_w1,*z_b1,*z_ln1_s,*z_ln1_b,*z_w2,*z_b2,*z_ln2_s,*z_ln2_b;
};

__device__ __forceinline__ float gelu_f(float x){
  float t = tanhf(0.7978845608028654f*(x + 0.044715f*x*x*x));
  return 0.5f*x*(1.0f+t);
}

// masked softmax over 5 slots, run by one lane. Matches reference masked_softmax.
__device__ void msm5(const float* lgv, const int* m, float* outp, float scale){
  bool any = m[0]||m[1]||m[2]||m[3]||m[4];
  if(!any){ for(int s2=0;s2<5;s2++) outp[s2]=0.f; return; }
  float mx=NEGB;
  for(int s2=0;s2<5;s2++) if(m[s2]) mx=fmaxf(mx, scale*lgv[s2]);
  float e[5], se=0.f;
  for(int s2=0;s2<5;s2++){ e[s2]= m[s2]? expf(scale*lgv[s2]-mx):0.f; se+=e[s2]; }
  float inv=1.f/se;
  for(int s2=0;s2<5;s2++) outp[s2]=e[s2]*inv;
}

// LayerNorm over 5 rows of 32 (slots); 2 rows per pass via the two 32-lane halves.
__device__ void ln5x32(const float* src, float* dst, const float* Sc, const float* Bi, int l){
  for (int sp=0; sp<6; sp+=2){
    int sl = sp + (l>>5), i = l&31;
    bool act = sl < SLOTS;
    float v = act ? src[sl*32+i] : 0.f;
    float sum=v;
    sum+=__shfl_xor(sum,16,32); sum+=__shfl_xor(sum,8,32); sum+=__shfl_xor(sum,4,32);
    sum+=__shfl_xor(sum,2,32);  sum+=__shfl_xor(sum,1,32);
    float mu=sum*(1.f/32.f);
    float d = v-mu;
    float q=d*d;
    q+=__shfl_xor(q,16,32); q+=__shfl_xor(q,8,32); q+=__shfl_xor(q,4,32);
    q+=__shfl_xor(q,2,32);  q+=__shfl_xor(q,1,32);
    float rstd=rsqrtf(q*(1.f/32.f)+1e-6f);
    if(act) dst[sl*32+i]=d*rstd*Sc[i]+Bi[i];
  }
}

struct TS {
  float xb[DX]; float ego[64]; float tv[160]; float yb[160];
  float qb[160]; float kb[160]; float vb[160]; float hb[320];
  float at[100]; float zb[ZDIM];
  float scs[5], wts[5], alp[5];
  float qeb[32], egh[32]; float lg[10], a2[10];
  int mk[5]; int mks[5];
};

#define WV 4
__global__ __launch_bounds__(256) void k_token(P p, float* __restrict__ outp) {
  __shared__ TS S[WV];
  __shared__ float h1[WV][128];
  __shared__ float h2[WV][128];
  int wid = threadIdx.x >> 6, l = threadIdx.x & 63;
  TS& s = S[wid];
  long tok = (long)blockIdx.x*WV + wid;

  const float* xr = p.x + (size_t)tok*DX;
  for (int i=l;i<DX;i+=64) s.xb[i] = xr[i];
  __syncthreads();

  // mask from r = nbr[...,0:3]
  if (l < SLOTS) { int nb = EGO_DD + l*PER;
    s.mk[l] = (fabsf(s.xb[nb])>1e-6f || fabsf(s.xb[nb+1])>1e-6f || fabsf(s.xb[nb+2])>1e-6f) ? 1 : 0; }
  __syncthreads();
  int nmask = s.mk[0]+s.mk[1]+s.mk[2]+s.mk[3]+s.mk[4];
  bool hasany = nmask>0;
  if (l < SLOTS) s.mks[l] = hasany ? s.mk[l] : (l==0 ? 1 : 0);

  // ego_e (z[0:64])
  { float a = p.b_ego[l];
    for (int k=0;k<EGO_DD;k++) a += s.xb[k]*p.w_ego[k*64+l];
    float g = gelu_f(a); s.ego[l]=g; s.zb[l]=g; }
  // pair_e (z[64:96])
  if (l<32){ float a = p.b_pair[l];
    for (int k=0;k<PAIR_DD;k++) a += s.xb[107+k]*p.w_pair[k*32+l];
    s.zb[64+l]=gelu_f(a); }
  // ter_e (z[96:160])
  { float a = p.b_ter[l];
    for (int k=0;k<TER_DD;k++) a += s.xb[117+k]*p.w_ter[k*64+l];
    s.zb[96+l]=gelu_f(a); }
  __syncthreads();

  // inv_tok
  for (int idx=l; idx<160; idx+=64){
    int sl=idx>>5, i=idx&31; float v=0.f;
    if (s.mk[sl]) {
      int nb=EGO_DD+sl*PER;
      float a0=s.xb[nb+6],a1=s.xb[nb+7],a2v=s.xb[nb+8];
      float iv[10]={s.xb[nb+9],s.xb[nb+10],s.xb[nb+11],s.xb[nb+12],s.xb[nb+13],s.xb[nb+14],
                    a0,a1,a2v,sqrtf(a0*a0+a1*a1+a2v*a2v)};
      float a=p.b_invtok[i];
      for(int k=0;k<10;k++) a += iv[k]*p.w_invtok[k*32+i];
      v = gelu_f(a);
    }
    s.tv[idx]=v;
  }
  __syncthreads();

  // ---- transformer: LN1 -> qkv
  ln5x32(s.tv, s.yb, p.ln1_s, p.ln1_b, l);
  __syncthreads();
  for (int idx=l; idx<160; idx+=64){
    int sl=idx>>5, i=idx&31;
    float aq=p.bq[i], ak=p.bk[i], av=p.bv[i];
    const float* y = &s.yb[sl*32];
    for(int k=0;k<32;k++){ float yv=y[k];
      aq+=yv*p.wq[k*32+i]; ak+=yv*p.wk[k*32+i]; av+=yv*p.wv[k*32+i]; }
    s.qb[idx]=aq; s.kb[idx]=ak; s.vb[idx]=av;
  }
  __syncthreads();
  // attention weights (20 lanes: h x q)
  if (l<20){
    int h=l/5, qs=l%5;
    float sc5[5]; float mx=NEGB;
    for(int ks=0;ks<5;ks++){
      float d8=0;
      for(int d=0;d<8;d++) d8 += s.qb[qs*32+h*8+d]*s.kb[ks*32+h*8+d];
      float v = (s.mks[qs]&&s.mks[ks]) ? d8*0.35355339059327373f : NEGB;
      sc5[ks]=v; mx=fmaxf(mx,v);
    }
    float se=0;
    for(int ks=0;ks<5;ks++){ float e=expf(sc5[ks]-mx); sc5[ks]=e; se+=e; }
    float inv=1.f/se;
    for(int ks=0;ks<5;ks++) s.at[(h*5+qs)*5+ks]=sc5[ks]*inv;
  }
  __syncthreads();
  // attn @ v
  for (int idx=l; idx<160; idx+=64){
    int sl=idx>>5, i=idx&31, h=i>>3, d=i&7;
    float o=0;
    for(int ks=0;ks<5;ks++) o += s.at[(h*5+sl)*5+ks]*s.vb[ks*32+h*8+d];
    s.yb[idx]=o;
  }
  __syncthreads();
  // out proj + residual (zero_masked)
  for (int idx=l; idx<160; idx+=64){
    int sl=idx>>5, i=idx&31;
    if (s.mk[sl]){ float a=p.bo[i];
      const float* y=&s.yb[sl*32];
      for(int k=0;k<32;k++) a += y[k]*p.wo[k*32+i];
      s.tv[idx] += a; }
  }
  __syncthreads();
  // LN2 + FFN
  ln5x32(s.tv, s.yb, p.ln2_s, p.ln2_b, l);
  __syncthreads();
  for (int idx=l; idx<320; idx+=64){
    int sl=idx>>6, j=idx&63;
    float a=p.b1[j];
    const float* y=&s.yb[sl*32];
    for(int k=0;k<32;k++) a += y[k]*p.w1[k*64+j];
    s.hb[idx]=gelu_f(a);
  }
  __syncthreads();
  for (int idx=l; idx<160; idx+=64){
    int sl=idx>>5, i=idx&31;
    float nv=0.f;
    if (s.mk[sl]){ float a=p.b2[i];
      const float* h=&s.hb[sl*64];
      for(int j=0;j<64;j++) a += h[j]*p.w2[j*32+i];
      nv = s.tv[idx]+a; }
    s.tv[idx]=nv;
  }
  __syncthreads();

  // pools: mean (z[160:192]) / max (z[192:224])
  if (l<32){
    float v0=s.tv[l],v1=s.tv[32+l],v2=s.tv[64+l],v3=s.tv[96+l],v4=s.tv[128+l];
    int cnt = nmask>0?nmask:1;
    s.zb[160+l]=(v0+v1+v2+v3+v4)/(float)cnt;
    float mx=-1e9f;
    if(s.mk[0])mx=fmaxf(mx,v0); if(s.mk[1])mx=fmaxf(mx,v1); if(s.mk[2])mx=fmaxf(mx,v2);
    if(s.mk[3])mx=fmaxf(mx,v3); if(s.mk[4])mx=fmaxf(mx,v4);
    s.zb[192+l]= hasany ? mx : 0.f;
  }
  // sp head (z[224:256])
  ln5x32(s.tv, s.yb, p.sp_ln_s, p.sp_ln_b, l);
  __syncthreads();
  if (l<SLOTS){ float a=p.sp_b[0];
    for(int i=0;i<32;i++) a += s.yb[l*32+i]*p.sp_w[i];
    s.scs[l]=a; }
  __syncthreads();
  if (l==0){
    float temp = log1pf(expf(p.sp_lt[0])) + 0.001f;
    msm5(s.scs, s.mk, s.wts, temp);
  }
  __syncthreads();
  if (l<32){ float a=0;
    for(int sl=0;sl<5;sl++) a += s.wts[sl]*s.tv[sl*32+l];
    s.zb[224+l]=a; }
  // ap head (z[256:288])
  if (l<32){ float a=p.ap_bq[l];
    for(int k=0;k<64;k++) a += s.ego[k]*p.ap_wq[k*32+l];
    s.qeb[l]=a; }
  __syncthreads();
  for (int idx=l; idx<160; idx+=64){
    int sl=idx>>5, i=idx&31;
    float a=p.ap_bk[i];
    const float* t=&s.tv[sl*32];
    for(int k=0;k<32;k++) a += t[k]*p.ap_wk[k*32+i];
    s.yb[idx]=tanhf(s.qeb[i]+a);
  }
  __syncthreads();
  if (l<SLOTS){ float a=p.ap_be[0];
    for(int i=0;i<32;i++) a += s.yb[l*32+i]*p.ap_we[i];
    s.scs[l]=a; }
  __syncthreads();
  if (l==0) msm5(s.scs, s.mk, s.alp, 1.f);
  __syncthreads();
  if (l<32){ float a=0;
    for(int sl=0;sl<5;sl++) a += s.alp[sl]*s.tv[sl*32+l];
    s.zb[256+l]=a; }
  // flat head (z[288:320]) on lanes 0..31, vr ego_h on lanes 32..63
  if (l<32){ float a=p.flat_b[l];
    for(int k=0;k<160;k++) a += s.tv[k]*p.flat_w[k*32+l];
    s.zb[288+l]=0.25f*gelu_f(a); }
  if (l>=32){ int i=l-32; float a=p.vr_bego[i];
    for(int k=0;k<64;k++) a += s.ego[k]*p.vr_wego[k*32+i];
    s.egh[i]=a; }
  // vr head (z[320:332])
  ln5x32(s.tv, s.yb, p.vr_ln_s, p.vr_ln_b, l);
  __syncthreads();
  for (int idx=l; idx<160; idx+=64){
    int sl=idx>>5, i=idx&31;
    float a=p.vr_bh[i];
    const float* y=&s.yb[sl*32];
    for(int k=0;k<32;k++) a += y[k]*p.vr_wh[k*32+i];
    for(int k=0;k<32;k++) a += s.egh[k]*p.vr_wh[(32+k)*32+i];
    s.qb[idx]=gelu_f(a);
  }
  __syncthreads();
  if (l<10){ int sl=l>>1, hh=l&1;
    float a=p.vr_bl[hh];
    for(int i=0;i<32;i++) a += s.qb[sl*32+i]*p.vr_wl[i*2+hh];
    s.lg[sl*2+hh]=a; }
  __syncthreads();
  if (l<2){ float tmp[5],o5[5];
    for(int sl=0;sl<5;sl++) tmp[sl]=s.lg[sl*2+l];
    msm5(tmp, s.mk, o5, 1.f);
    for(int sl=0;sl<5;sl++) s.a2[sl*2+l]=o5[sl]; }
  __syncthreads();
  if (l<12){ int w = l/6, rem=l%6, hh=rem/3, d=rem%3;
    float a=0;
    for(int sl=0;sl<5;sl++) a += s.a2[sl*2+hh]*s.xb[EGO_DD+sl*PER + w*3 + d];
    s.zb[320 + w*6 + hh*3 + d]=a; }
  __syncthreads();   // z[4][332] complete in LDS for all 4 waves

  // ---- fused z-phase: h1 = gelu(z @ z_w1 + b1)  (block-cooperative GEMM)
  {
    int tid = threadIdx.x;
    int c = tid & 127, pr = tid >> 7;          // column, token-pair
    int t0i = pr*2, t1i = pr*2+1;
    float a0 = p.z_b1[c], a1 = a0;
    const float* zb0 = S[t0i].zb;
    const float* zb1 = S[t1i].zb;
    for (int k=0;k<ZDIM;k++){
      float w = p.z_w1[k*128+c];
      a0 += zb0[k]*w; a1 += zb1[k]*w;
    }
    h1[t0i][c] = gelu_f(a0);
    h1[t1i][c] = gelu_f(a1);
  }
  __syncthreads();
  // LN1 per wave on its own token (128 elems, 2 per lane)
  {
    float v0 = h1[wid][l], v1 = h1[wid][l+64];
    float sum = v0+v1;
    for (int o=32;o>=1;o>>=1) sum += __shfl_xor(sum,o,64);
    float mu = sum*(1.f/128.f);
    float d0=v0-mu, d1=v1-mu;
    float q = d0*d0+d1*d1;
    for (int o=32;o>=1;o>>=1) q += __shfl_xor(q,o,64);
    float rs = rsqrtf(q*(1.f/128.f)+1e-6f);
    h1[wid][l]    = d0*rs*p.z_ln1_s[l]   +p.z_ln1_b[l];
    h1[wid][l+64] = d1*rs*p.z_ln1_s[l+64]+p.z_ln1_b[l+64];
  }
  __syncthreads();
  // h2 = gelu(h1n @ z_w2 + b2)
  {
    int tid = threadIdx.x;
    int c = tid & 127, pr = tid >> 7;
    int t0i = pr*2, t1i = pr*2+1;
    float a0 = p.z_b2[c], a1 = a0;
    const float* y0 = h1[t0i];
    const float* y1 = h1[t1i];
    for (int k=0;k<128;k++){
      float w = p.z_w2[k*128+c];
      a0 += y0[k]*w; a1 += y1[k]*w;
    }
    h2[t0i][c] = gelu_f(a0);
    h2[t1i][c] = gelu_f(a1);
  }
  __syncthreads();
  // LN2 per wave + store
  {
    float v0 = h2[wid][l], v1 = h2[wid][l+64];
    float sum = v0+v1;
    for (int o=32;o>=1;o>>=1) sum += __shfl_xor(sum,o,64);
    float mu = sum*(1.f/128.f);
    float d0=v0-mu, d1=v1-mu;
    float q = d0*d0+d1*d1;
    for (int o=32;o>=1;o>>=1) q += __shfl_xor(q,o,64);
    float rs = rsqrtf(q*(1.f/128.f)+1e-6f);
    float o0 = d0*rs*p.z_ln2_s[l]   +p.z_ln2_b[l];
    float o1 = d1*rs*p.z_ln2_s[l+64]+p.z_ln2_b[l+64];
    float* op = outp + (size_t)tok*128;
    op[l]    = o0;
    op[l+64] = o1;
  }
}

extern "C" void kernel_launch(void* const* d_in, const int* in_sizes, int n_in,
                              void* d_out, int out_size, void* d_ws, size_t ws_size,
                              hipStream_t stream) {
  (void)in_sizes; (void)n_in; (void)out_size; (void)d_ws; (void)ws_size;
  P p;
  const void** pp = (const void**)&p;
  for (int i=0;i<54;i++) pp[i] = d_in[i];
  k_token<<<NTOK/WV, 256, 0, stream>>>(p, (float*)d_out);
}

// Round 4
// 2434.675 us; speedup vs baseline: 1.1775x; 1.1775x over previous
//
#include <hip/hip_runtime.h>
#include <hip/hip_bf16.h>

#define SLOTS 5
#define PER 15
#define EGO_DD 32
#define PAIR_DD 10
#define TER_DD 81
#define DX 198
#define ZDIM 332
#define NTOK (64*2048)
#define NEGB (-3.402823466e38f)

// packed bf16 B-fragment workspace: B1 = 11 ktiles * 8 ntiles * 64 lanes * 8
#define B1_ELEMS (11*8*64*8)
#define B2_ELEMS (4*8*64*8)
#define WS_NEED ((B1_ELEMS + B2_ELEMS) * 2)

typedef float f32x4 __attribute__((ext_vector_type(4)));
typedef short s16x8 __attribute__((ext_vector_type(8)));

struct P {
  const float *x,*w_ego,*b_ego,*w_pair,*b_pair,*w_ter,*b_ter,*w_invtok,*b_invtok,
    *ln1_s,*ln1_b,*wq,*bq,*wk,*bk,*wv,*bv,*wo,*bo,*ln2_s,*ln2_b,*w1,*b1,*w2,*b2,
    *sp_ln_s,*sp_ln_b,*sp_w,*sp_b,*sp_lt,*ap_wq,*ap_bq,*ap_wk,*ap_bk,*ap_we,*ap_be,
    *flat_w,*flat_b,*vr_wego,*vr_bego,*vr_ln_s,*vr_ln_b,*vr_wh,*vr_bh,*vr_wl,*vr_bl,
    *z_w1,*z_b1,*z_ln1_s,*z_ln1_b,*z_w2,*z_b2,*z_ln2_s,*z_ln2_b;
};

__device__ __forceinline__ float gelu_f(float x){
  float t = tanhf(0.7978845608028654f*(x + 0.044715f*x*x*x));
  return 0.5f*x*(1.0f+t);
}
__device__ __forceinline__ short f2bf(float x){
  __hip_bfloat16 h = __float2bfloat16(x);
  return *reinterpret_cast<short*>(&h);
}

// masked softmax over 5 slots, run by one lane. Matches reference masked_softmax.
__device__ void msm5(const float* lgv, const int* m, float* outp, float scale){
  bool any = m[0]||m[1]||m[2]||m[3]||m[4];
  if(!any){ for(int s2=0;s2<5;s2++) outp[s2]=0.f; return; }
  float mx=NEGB;
  for(int s2=0;s2<5;s2++) if(m[s2]) mx=fmaxf(mx, scale*lgv[s2]);
  float e[5], se=0.f;
  for(int s2=0;s2<5;s2++){ e[s2]= m[s2]? expf(scale*lgv[s2]-mx):0.f; se+=e[s2]; }
  float inv=1.f/se;
  for(int s2=0;s2<5;s2++) outp[s2]=e[s2]*inv;
}

// LayerNorm over 5 rows of 32 (slots); 2 rows per pass via the two 32-lane halves.
__device__ void ln5x32(const float* src, float* dst, const float* Sc, const float* Bi, int l){
  for (int sp=0; sp<6; sp+=2){
    int sl = sp + (l>>5), i = l&31;
    bool act = sl < SLOTS;
    float v = act ? src[sl*32+i] : 0.f;
    float sum=v;
    sum+=__shfl_xor(sum,16,32); sum+=__shfl_xor(sum,8,32); sum+=__shfl_xor(sum,4,32);
    sum+=__shfl_xor(sum,2,32);  sum+=__shfl_xor(sum,1,32);
    float mu=sum*(1.f/32.f);
    float d = v-mu;
    float q=d*d;
    q+=__shfl_xor(q,16,32); q+=__shfl_xor(q,8,32); q+=__shfl_xor(q,4,32);
    q+=__shfl_xor(q,2,32);  q+=__shfl_xor(q,1,32);
    float rstd=rsqrtf(q*(1.f/32.f)+1e-6f);
    if(act) dst[sl*32+i]=d*rstd*Sc[i]+Bi[i];
  }
}

struct TS {
  float xb[DX]; float ego[64]; float tv[160]; float yb[160];
  float qb[160]; float kb[160]; float vb[160]; float hb[320];
  float at[100]; float zb[ZDIM];
  float scs[5], wts[5], alp[5];
  float qeb[32], egh[32]; float lg[10], a2[10];
  int mk[5]; int mks[5];
};

// pack z_w1/z_w2 (fp32, [K][128]) into bf16 MFMA B-fragment order:
// off = ((kt*8+nt)*64 + lane)*8 + j ; k = kt*32 + (lane>>4)*8 + j ; n = nt*16 + (lane&15)
__global__ __launch_bounds__(256) void k_prep(const float* __restrict__ w1,
                                              const float* __restrict__ w2,
                                              short* __restrict__ ws){
  int idx = blockIdx.x*256 + threadIdx.x;
  if (idx < B1_ELEMS){
    int j = idx & 7, lane = (idx>>3)&63, nt = (idx>>9)&7, kt = idx>>12;
    int k = kt*32 + ((lane>>4)<<3) + j, n = nt*16 + (lane&15);
    float v = (k < ZDIM) ? w1[k*128+n] : 0.f;
    ws[idx] = f2bf(v);
  } else if (idx < B1_ELEMS + B2_ELEMS){
    int t = idx - B1_ELEMS;
    int j = t & 7, lane = (t>>3)&63, nt = (t>>9)&7, kt = t>>12;
    int k = kt*32 + ((lane>>4)<<3) + j, n = nt*16 + (lane&15);
    ws[idx] = f2bf(w2[k*128+n]);
  }
}

#define WV 4
template<int ZP>
__global__ __launch_bounds__(256) void k_token(P p, float* __restrict__ outp,
                                               const short* __restrict__ wsb) {
  __shared__ TS S[WV];
  __shared__ float h1[WV][128];
  __shared__ float h2[WV][128];
  int wid = threadIdx.x >> 6, l = threadIdx.x & 63;
  TS& s = S[wid];
  long tok = (long)blockIdx.x*WV + wid;

  const float* xr = p.x + (size_t)tok*DX;
  for (int i=l;i<DX;i+=64) s.xb[i] = xr[i];
  __syncthreads();

  // mask from r = nbr[...,0:3]
  if (l < SLOTS) { int nb = EGO_DD + l*PER;
    s.mk[l] = (fabsf(s.xb[nb])>1e-6f || fabsf(s.xb[nb+1])>1e-6f || fabsf(s.xb[nb+2])>1e-6f) ? 1 : 0; }
  __syncthreads();
  int nmask = s.mk[0]+s.mk[1]+s.mk[2]+s.mk[3]+s.mk[4];
  bool hasany = nmask>0;
  if (l < SLOTS) s.mks[l] = hasany ? s.mk[l] : (l==0 ? 1 : 0);

  // ego_e (z[0:64])
  { float a = p.b_ego[l];
    for (int k=0;k<EGO_DD;k++) a += s.xb[k]*p.w_ego[k*64+l];
    float g = gelu_f(a); s.ego[l]=g; s.zb[l]=g; }
  // pair_e (z[64:96])
  if (l<32){ float a = p.b_pair[l];
    for (int k=0;k<PAIR_DD;k++) a += s.xb[107+k]*p.w_pair[k*32+l];
    s.zb[64+l]=gelu_f(a); }
  // ter_e (z[96:160])
  { float a = p.b_ter[l];
    for (int k=0;k<TER_DD;k++) a += s.xb[117+k]*p.w_ter[k*64+l];
    s.zb[96+l]=gelu_f(a); }
  __syncthreads();

  // inv_tok
  for (int idx=l; idx<160; idx+=64){
    int sl=idx>>5, i=idx&31; float v=0.f;
    if (s.mk[sl]) {
      int nb=EGO_DD+sl*PER;
      float a0=s.xb[nb+6],a1=s.xb[nb+7],a2v=s.xb[nb+8];
      float iv[10]={s.xb[nb+9],s.xb[nb+10],s.xb[nb+11],s.xb[nb+12],s.xb[nb+13],s.xb[nb+14],
                    a0,a1,a2v,sqrtf(a0*a0+a1*a1+a2v*a2v)};
      float a=p.b_invtok[i];
      for(int k=0;k<10;k++) a += iv[k]*p.w_invtok[k*32+i];
      v = gelu_f(a);
    }
    s.tv[idx]=v;
  }
  __syncthreads();

  // ---- transformer: LN1 -> qkv
  ln5x32(s.tv, s.yb, p.ln1_s, p.ln1_b, l);
  __syncthreads();
  for (int idx=l; idx<160; idx+=64){
    int sl=idx>>5, i=idx&31;
    float aq=p.bq[i], ak=p.bk[i], av=p.bv[i];
    const float* y = &s.yb[sl*32];
    for(int k=0;k<32;k++){ float yv=y[k];
      aq+=yv*p.wq[k*32+i]; ak+=yv*p.wk[k*32+i]; av+=yv*p.wv[k*32+i]; }
    s.qb[idx]=aq; s.kb[idx]=ak; s.vb[idx]=av;
  }
  __syncthreads();
  // attention weights (20 lanes: h x q)
  if (l<20){
    int h=l/5, qs=l%5;
    float sc5[5]; float mx=NEGB;
    for(int ks=0;ks<5;ks++){
      float d8=0;
      for(int d=0;d<8;d++) d8 += s.qb[qs*32+h*8+d]*s.kb[ks*32+h*8+d];
      float v = (s.mks[qs]&&s.mks[ks]) ? d8*0.35355339059327373f : NEGB;
      sc5[ks]=v; mx=fmaxf(mx,v);
    }
    float se=0;
    for(int ks=0;ks<5;ks++){ float e=expf(sc5[ks]-mx); sc5[ks]=e; se+=e; }
    float inv=1.f/se;
    for(int ks=0;ks<5;ks++) s.at[(h*5+qs)*5+ks]=sc5[ks]*inv;
  }
  __syncthreads();
  // attn @ v
  for (int idx=l; idx<160; idx+=64){
    int sl=idx>>5, i=idx&31, h=i>>3, d=i&7;
    float o=0;
    for(int ks=0;ks<5;ks++) o += s.at[(h*5+sl)*5+ks]*s.vb[ks*32+h*8+d];
    s.yb[idx]=o;
  }
  __syncthreads();
  // out proj + residual (zero_masked)
  for (int idx=l; idx<160; idx+=64){
    int sl=idx>>5, i=idx&31;
    if (s.mk[sl]){ float a=p.bo[i];
      const float* y=&s.yb[sl*32];
      for(int k=0;k<32;k++) a += y[k]*p.wo[k*32+i];
      s.tv[idx] += a; }
  }
  __syncthreads();
  // LN2 + FFN
  ln5x32(s.tv, s.yb, p.ln2_s, p.ln2_b, l);
  __syncthreads();
  for (int idx=l; idx<320; idx+=64){
    int sl=idx>>6, j=idx&63;
    float a=p.b1[j];
    const float* y=&s.yb[sl*32];
    for(int k=0;k<32;k++) a += y[k]*p.w1[k*64+j];
    s.hb[idx]=gelu_f(a);
  }
  __syncthreads();
  for (int idx=l; idx<160; idx+=64){
    int sl=idx>>5, i=idx&31;
    float nv=0.f;
    if (s.mk[sl]){ float a=p.b2[i];
      const float* h=&s.hb[sl*64];
      for(int j=0;j<64;j++) a += h[j]*p.w2[j*32+i];
      nv = s.tv[idx]+a; }
    s.tv[idx]=nv;
  }
  __syncthreads();

  // pools: mean (z[160:192]) / max (z[192:224])
  if (l<32){
    float v0=s.tv[l],v1=s.tv[32+l],v2=s.tv[64+l],v3=s.tv[96+l],v4=s.tv[128+l];
    int cnt = nmask>0?nmask:1;
    s.zb[160+l]=(v0+v1+v2+v3+v4)/(float)cnt;
    float mx=-1e9f;
    if(s.mk[0])mx=fmaxf(mx,v0); if(s.mk[1])mx=fmaxf(mx,v1); if(s.mk[2])mx=fmaxf(mx,v2);
    if(s.mk[3])mx=fmaxf(mx,v3); if(s.mk[4])mx=fmaxf(mx,v4);
    s.zb[192+l]= hasany ? mx : 0.f;
  }
  // sp head (z[224:256])
  ln5x32(s.tv, s.yb, p.sp_ln_s, p.sp_ln_b, l);
  __syncthreads();
  if (l<SLOTS){ float a=p.sp_b[0];
    for(int i=0;i<32;i++) a += s.yb[l*32+i]*p.sp_w[i];
    s.scs[l]=a; }
  __syncthreads();
  if (l==0){
    float temp = log1pf(expf(p.sp_lt[0])) + 0.001f;
    msm5(s.scs, s.mk, s.wts, temp);
  }
  __syncthreads();
  if (l<32){ float a=0;
    for(int sl=0;sl<5;sl++) a += s.wts[sl]*s.tv[sl*32+l];
    s.zb[224+l]=a; }
  // ap head (z[256:288])
  if (l<32){ float a=p.ap_bq[l];
    for(int k=0;k<64;k++) a += s.ego[k]*p.ap_wq[k*32+l];
    s.qeb[l]=a; }
  __syncthreads();
  for (int idx=l; idx<160; idx+=64){
    int sl=idx>>5, i=idx&31;
    float a=p.ap_bk[i];
    const float* t=&s.tv[sl*32];
    for(int k=0;k<32;k++) a += t[k]*p.ap_wk[k*32+i];
    s.yb[idx]=tanhf(s.qeb[i]+a);
  }
  __syncthreads();
  if (l<SLOTS){ float a=p.ap_be[0];
    for(int i=0;i<32;i++) a += s.yb[l*32+i]*p.ap_we[i];
    s.scs[l]=a; }
  __syncthreads();
  if (l==0) msm5(s.scs, s.mk, s.alp, 1.f);
  __syncthreads();
  if (l<32){ float a=0;
    for(int sl=0;sl<5;sl++) a += s.alp[sl]*s.tv[sl*32+l];
    s.zb[256+l]=a; }
  // flat head (z[288:320]) on lanes 0..31, vr ego_h on lanes 32..63
  if (l<32){ float a=p.flat_b[l];
    for(int k=0;k<160;k++) a += s.tv[k]*p.flat_w[k*32+l];
    s.zb[288+l]=0.25f*gelu_f(a); }
  if (l>=32){ int i=l-32; float a=p.vr_bego[i];
    for(int k=0;k<64;k++) a += s.ego[k]*p.vr_wego[k*32+i];
    s.egh[i]=a; }
  // vr head (z[320:332])
  ln5x32(s.tv, s.yb, p.vr_ln_s, p.vr_ln_b, l);
  __syncthreads();
  for (int idx=l; idx<160; idx+=64){
    int sl=idx>>5, i=idx&31;
    float a=p.vr_bh[i];
    const float* y=&s.yb[sl*32];
    for(int k=0;k<32;k++) a += y[k]*p.vr_wh[k*32+i];
    for(int k=0;k<32;k++) a += s.egh[k]*p.vr_wh[(32+k)*32+i];
    s.qb[idx]=gelu_f(a);
  }
  __syncthreads();
  if (l<10){ int sl=l>>1, hh=l&1;
    float a=p.vr_bl[hh];
    for(int i=0;i<32;i++) a += s.qb[sl*32+i]*p.vr_wl[i*2+hh];
    s.lg[sl*2+hh]=a; }
  __syncthreads();
  if (l<2){ float tmp[5],o5[5];
    for(int sl=0;sl<5;sl++) tmp[sl]=s.lg[sl*2+l];
    msm5(tmp, s.mk, o5, 1.f);
    for(int sl=0;sl<5;sl++) s.a2[sl*2+l]=o5[sl]; }
  __syncthreads();
  if (l<12){ int w = l/6, rem=l%6, hh=rem/3, d=rem%3;
    float a=0;
    for(int sl=0;sl<5;sl++) a += s.a2[sl*2+hh]*s.xb[EGO_DD+sl*PER + w*3 + d];
    s.zb[320 + w*6 + hh*3 + d]=a; }
  __syncthreads();   // z[4][332] complete in LDS for all 4 waves

  // ---- fused z-phase
  if constexpr (ZP == 1) {
    // MFMA path: D[m=token(4 of 16)][n=col], wave handles ntiles {2*wid, 2*wid+1}
    const s16x8* B1 = (const s16x8*)wsb;          // [kt][nt][lane]
    const s16x8* B2 = B1 + 11*8*64/ /*per s16x8*/ 1; // advance by B1_ELEMS/8 vectors
    B2 = (const s16x8*)(wsb + B1_ELEMS);
    int m = l & 15, q = l >> 4;
    // GEMM1: K = 352 (11 ktiles), A = zb (4 valid rows)
    f32x4 acc0 = {0.f,0.f,0.f,0.f}, acc1 = {0.f,0.f,0.f,0.f};
    for (int kt=0; kt<11; kt++){
      s16x8 af;
      int k0 = kt*32 + q*8;
      if (m < 4){
        const float* zrow = S[m].zb;
        #pragma unroll
        for (int j=0;j<8;j++){ int kk=k0+j; af[j] = (kk<ZDIM) ? f2bf(zrow[kk]) : (short)0; }
      } else {
        #pragma unroll
        for (int j=0;j<8;j++) af[j]=0;
      }
      s16x8 b0 = B1[(kt*8 + 2*wid  )*64 + l];
      s16x8 b1 = B1[(kt*8 + 2*wid+1)*64 + l];
      acc0 = __builtin_amdgcn_mfma_f32_16x16x32_bf16(af, b0, acc0, 0,0,0);
      acc1 = __builtin_amdgcn_mfma_f32_16x16x32_bf16(af, b1, acc1, 0,0,0);
    }
    if (q == 0){
      int c0 = 2*wid*16 + m, c1 = (2*wid+1)*16 + m;
      float bb0 = p.z_b1[c0], bb1 = p.z_b1[c1];
      #pragma unroll
      for (int r=0;r<4;r++){
        h1[r][c0] = gelu_f(acc0[r] + bb0);
        h1[r][c1] = gelu_f(acc1[r] + bb1);
      }
    }
    __syncthreads();
    // LN1 per wave on its own token
    {
      float v0 = h1[wid][l], v1 = h1[wid][l+64];
      float sum = v0+v1;
      for (int o=32;o>=1;o>>=1) sum += __shfl_xor(sum,o,64);
      float mu = sum*(1.f/128.f);
      float d0=v0-mu, d1=v1-mu;
      float qq = d0*d0+d1*d1;
      for (int o=32;o>=1;o>>=1) qq += __shfl_xor(qq,o,64);
      float rs = rsqrtf(qq*(1.f/128.f)+1e-6f);
      h1[wid][l]    = d0*rs*p.z_ln1_s[l]   +p.z_ln1_b[l];
      h1[wid][l+64] = d1*rs*p.z_ln1_s[l+64]+p.z_ln1_b[l+64];
    }
    __syncthreads();
    // GEMM2: K = 128 (4 ktiles), A = h1 (4 valid rows)
    acc0 = (f32x4){0.f,0.f,0.f,0.f}; acc1 = (f32x4){0.f,0.f,0.f,0.f};
    for (int kt=0; kt<4; kt++){
      s16x8 af;
      int k0 = kt*32 + q*8;
      if (m < 4){
        const float* hrow = h1[m];
        #pragma unroll
        for (int j=0;j<8;j++) af[j] = f2bf(hrow[k0+j]);
      } else {
        #pragma unroll
        for (int j=0;j<8;j++) af[j]=0;
      }
      s16x8 b0 = B2[(kt*8 + 2*wid  )*64 + l];
      s16x8 b1 = B2[(kt*8 + 2*wid+1)*64 + l];
      acc0 = __builtin_amdgcn_mfma_f32_16x16x32_bf16(af, b0, acc0, 0,0,0);
      acc1 = __builtin_amdgcn_mfma_f32_16x16x32_bf16(af, b1, acc1, 0,0,0);
    }
    if (q == 0){
      int c0 = 2*wid*16 + m, c1 = (2*wid+1)*16 + m;
      float bb0 = p.z_b2[c0], bb1 = p.z_b2[c1];
      #pragma unroll
      for (int r=0;r<4;r++){
        h2[r][c0] = gelu_f(acc0[r] + bb0);
        h2[r][c1] = gelu_f(acc1[r] + bb1);
      }
    }
    __syncthreads();
  } else {
    // scalar fallback z-phase
    {
      int tid = threadIdx.x;
      int c = tid & 127, pr = tid >> 7;
      int t0i = pr*2, t1i = pr*2+1;
      float a0 = p.z_b1[c], a1 = a0;
      const float* zb0 = S[t0i].zb;
      const float* zb1 = S[t1i].zb;
      for (int k=0;k<ZDIM;k++){
        float w = p.z_w1[k*128+c];
        a0 += zb0[k]*w; a1 += zb1[k]*w;
      }
      h1[t0i][c] = gelu_f(a0);
      h1[t1i][c] = gelu_f(a1);
    }
    __syncthreads();
    {
      float v0 = h1[wid][l], v1 = h1[wid][l+64];
      float sum = v0+v1;
      for (int o=32;o>=1;o>>=1) sum += __shfl_xor(sum,o,64);
      float mu = sum*(1.f/128.f);
      float d0=v0-mu, d1=v1-mu;
      float qq = d0*d0+d1*d1;
      for (int o=32;o>=1;o>>=1) qq += __shfl_xor(qq,o,64);
      float rs = rsqrtf(qq*(1.f/128.f)+1e-6f);
      h1[wid][l]    = d0*rs*p.z_ln1_s[l]   +p.z_ln1_b[l];
      h1[wid][l+64] = d1*rs*p.z_ln1_s[l+64]+p.z_ln1_b[l+64];
    }
    __syncthreads();
    {
      int tid = threadIdx.x;
      int c = tid & 127, pr = tid >> 7;
      int t0i = pr*2, t1i = pr*2+1;
      float a0 = p.z_b2[c], a1 = a0;
      const float* y0 = h1[t0i];
      const float* y1 = h1[t1i];
      for (int k=0;k<128;k++){
        float w = p.z_w2[k*128+c];
        a0 += y0[k]*w; a1 += y1[k]*w;
      }
      h2[t0i][c] = gelu_f(a0);
      h2[t1i][c] = gelu_f(a1);
    }
    __syncthreads();
  }

  // LN2 per wave + store
  {
    float v0 = h2[wid][l], v1 = h2[wid][l+64];
    float sum = v0+v1;
    for (int o=32;o>=1;o>>=1) sum += __shfl_xor(sum,o,64);
    float mu = sum*(1.f/128.f);
    float d0=v0-mu, d1=v1-mu;
    float q = d0*d0+d1*d1;
    for (int o=32;o>=1;o>>=1) q += __shfl_xor(q,o,64);
    float rs = rsqrtf(q*(1.f/128.f)+1e-6f);
    float o0 = d0*rs*p.z_ln2_s[l]   +p.z_ln2_b[l];
    float o1 = d1*rs*p.z_ln2_s[l+64]+p.z_ln2_b[l+64];
    float* op = outp + (size_t)tok*128;
    op[l]    = o0;
    op[l+64] = o1;
  }
}

extern "C" void kernel_launch(void* const* d_in, const int* in_sizes, int n_in,
                              void* d_out, int out_size, void* d_ws, size_t ws_size,
                              hipStream_t stream) {
  (void)in_sizes; (void)n_in; (void)out_size;
  P p;
  const void** pp = (const void**)&p;
  for (int i=0;i<54;i++) pp[i] = d_in[i];
  bool mfma_ok = (ws_size >= WS_NEED) && (d_ws != nullptr);
  if (mfma_ok) {
    short* wsb = (short*)d_ws;
    k_prep<<<(B1_ELEMS+B2_ELEMS+255)/256, 256, 0, stream>>>(p.z_w1, p.z_w2, wsb);
    k_token<1><<<NTOK/WV, 256, 0, stream>>>(p, (float*)d_out, wsb);
  } else {
    k_token<0><<<NTOK/WV, 256, 0, stream>>>(p, (float*)d_out, nullptr);
  }
}

// Round 5
// 1588.749 us; speedup vs baseline: 1.8045x; 1.5324x over previous
//
#include <hip/hip_runtime.h>
#include <hip/hip_bf16.h>

#define SLOTS 5
#define PER 15
#define EGO_DD 32
#define PAIR_DD 10
#define TER_DD 81
#define DX 198
#define ZDIM 332
#define NTOK (64*2048)
#define NEGB (-3.402823466e38f)
#define ST 36      // padded stride for [5][32] slot arrays (bank-conflict-free packs)
#define HBST 68    // padded stride for [5][64] ffn hidden

// ---- B-fragment tile table (tile = 64 lanes x 8 bf16 = 512 elems) ----
// generic layout: tile t0 + ktIdx*ntc + ntIdx ; k = ktIdx*32 + quad*8 + j ; n = ntIdx*16 + (lane&15)
#define T_EGO   0    // 32x64  kt1 nt4
#define T_PAIR  4    // 10x32  kt1 nt2
#define T_TER   6    // 81x64  kt3 nt4
#define T_INV   18   // 10x32  kt1 nt2
#define T_Q     20   // 32x32  kt1 nt2
#define T_K     22
#define T_V     24
#define T_O     26
#define T_W1    28   // 32x64  kt1 nt4
#define T_W2    32   // 64x32  kt2 nt2
#define T_APQ   36   // 64x32  kt2 nt2
#define T_APK   40   // 32x32  kt1 nt2
#define T_FLAT  42   // 160x32 kt5 nt2
#define T_VEGO  52   // 64x32  kt2 nt2
#define T_VH    56   // 64x32  kt2 nt2
#define T_ZW1   60   // 332x128 kt11 nt8
#define T_ZW2   148  // 128x128 kt4 nt8
#define T_TOT   180
#define WS_NEED (T_TOT*512*2)

typedef float f32x4 __attribute__((ext_vector_type(4)));
typedef short s16x8 __attribute__((ext_vector_type(8)));
#define MFMA(a,b,c) __builtin_amdgcn_mfma_f32_16x16x32_bf16(a,b,c,0,0,0)

struct P {
  const float *x,*w_ego,*b_ego,*w_pair,*b_pair,*w_ter,*b_ter,*w_invtok,*b_invtok,
    *ln1_s,*ln1_b,*wq,*bq,*wk,*bk,*wv,*bv,*wo,*bo,*ln2_s,*ln2_b,*w1,*b1,*w2,*b2,
    *sp_ln_s,*sp_ln_b,*sp_w,*sp_b,*sp_lt,*ap_wq,*ap_bq,*ap_wk,*ap_bk,*ap_we,*ap_be,
    *flat_w,*flat_b,*vr_wego,*vr_bego,*vr_ln_s,*vr_ln_b,*vr_wh,*vr_bh,*vr_wl,*vr_bl,
    *z_w1,*z_b1,*z_ln1_s,*z_ln1_b,*z_w2,*z_b2,*z_ln2_s,*z_ln2_b;
};

__device__ __forceinline__ short f2bf(float x){
  __hip_bfloat16 h = __float2bfloat16(x);
  return *reinterpret_cast<short*>(&h);
}
__device__ __forceinline__ float tanh_f(float x){
  float e = __expf(2.f*x);
  return 1.f - 2.f/(e+1.f);
}
__device__ __forceinline__ float gelu_f(float x){
  return 0.5f*x*(1.f+tanh_f(0.7978845608028654f*(x + 0.044715f*x*x*x)));
}
__device__ __forceinline__ s16x8 packrow(const float* r){
  s16x8 af;
  #pragma unroll
  for(int j=0;j<8;j++) af[j]=f2bf(r[j]);
  return af;
}
__device__ __forceinline__ s16x8 packrowb(const float* r, int k0, int K){
  s16x8 af;
  #pragma unroll
  for(int j=0;j<8;j++) af[j] = (k0+j<K) ? f2bf(r[k0+j]) : (short)0;
  return af;
}

// masked softmax over 5 slots, one lane.
__device__ void msm5(const float* lgv, const int* m, float* outp, float scale){
  bool any = m[0]||m[1]||m[2]||m[3]||m[4];
  if(!any){ for(int s2=0;s2<5;s2++) outp[s2]=0.f; return; }
  float mx=NEGB;
  for(int s2=0;s2<5;s2++) if(m[s2]) mx=fmaxf(mx, scale*lgv[s2]);
  float e[5], se=0.f;
  for(int s2=0;s2<5;s2++){ e[s2]= m[s2]? __expf(scale*lgv[s2]-mx):0.f; se+=e[s2]; }
  float inv=1.f/se;
  for(int s2=0;s2<5;s2++) outp[s2]=e[s2]*inv;
}

// LayerNorm over 5 rows of 32 (stride ST)
__device__ void ln5x32(const float* src, float* dst, const float* Sc, const float* Bi, int l){
  for (int sp=0; sp<6; sp+=2){
    int sl = sp + (l>>5), i = l&31;
    bool act = sl < SLOTS;
    float v = act ? src[sl*ST+i] : 0.f;
    float sum=v;
    sum+=__shfl_xor(sum,16,32); sum+=__shfl_xor(sum,8,32); sum+=__shfl_xor(sum,4,32);
    sum+=__shfl_xor(sum,2,32);  sum+=__shfl_xor(sum,1,32);
    float mu=sum*(1.f/32.f);
    float d = v-mu;
    float q=d*d;
    q+=__shfl_xor(q,16,32); q+=__shfl_xor(q,8,32); q+=__shfl_xor(q,4,32);
    q+=__shfl_xor(q,2,32);  q+=__shfl_xor(q,1,32);
    float rstd=rsqrtf(q*(1.f/32.f)+1e-6f);
    if(act) dst[sl*ST+i]=d*rstd*Sc[i]+Bi[i];
  }
}

struct __align__(16) TS {
  float ego[64];
  float tv[5*ST]; float yb[5*ST]; float qb[5*ST]; float kb[5*ST]; float vb[5*ST];
  float hb[5*HBST];
  float at[100];
  float zb[ZDIM];
  float qeb[32], egh[32];
  float xb[200];
  float scs[5], wts[5], alp[5], lg[10], a2[10];
  int mk[5], mks[5];
};

// pack all weights into bf16 B-fragments
__global__ __launch_bounds__(256) void k_prep(P p, short* __restrict__ ws){
  int idx = blockIdx.x*256 + threadIdx.x;
  if (idx >= T_TOT*512) return;
  int j = idx & 7, lane = (idx>>3)&63, tile = idx>>9;
  const float* src; int K,N,ntc,t0;
  if      (tile < T_PAIR){ src=p.w_ego;   K=32;  N=64;  ntc=4; t0=T_EGO; }
  else if (tile < T_TER ){ src=p.w_pair;  K=10;  N=32;  ntc=2; t0=T_PAIR; }
  else if (tile < T_INV ){ src=p.w_ter;   K=81;  N=64;  ntc=4; t0=T_TER; }
  else if (tile < T_Q   ){ src=p.w_invtok;K=10;  N=32;  ntc=2; t0=T_INV; }
  else if (tile < T_K   ){ src=p.wq;      K=32;  N=32;  ntc=2; t0=T_Q; }
  else if (tile < T_V   ){ src=p.wk;      K=32;  N=32;  ntc=2; t0=T_K; }
  else if (tile < T_O   ){ src=p.wv;      K=32;  N=32;  ntc=2; t0=T_V; }
  else if (tile < T_W1  ){ src=p.wo;      K=32;  N=32;  ntc=2; t0=T_O; }
  else if (tile < T_W2  ){ src=p.w1;      K=32;  N=64;  ntc=4; t0=T_W1; }
  else if (tile < T_APQ ){ src=p.w2;      K=64;  N=32;  ntc=2; t0=T_W2; }
  else if (tile < T_APK ){ src=p.ap_wq;   K=64;  N=32;  ntc=2; t0=T_APQ; }
  else if (tile < T_FLAT){ src=p.ap_wk;   K=32;  N=32;  ntc=2; t0=T_APK; }
  else if (tile < T_VEGO){ src=p.flat_w;  K=160; N=32;  ntc=2; t0=T_FLAT; }
  else if (tile < T_VH  ){ src=p.vr_wego; K=64;  N=32;  ntc=2; t0=T_VEGO; }
  else if (tile < T_ZW1 ){ src=p.vr_wh;   K=64;  N=32;  ntc=2; t0=T_VH; }
  else if (tile < T_ZW2 ){ src=p.z_w1;    K=ZDIM;N=128; ntc=8; t0=T_ZW1; }
  else                   { src=p.z_w2;    K=128; N=128; ntc=8; t0=T_ZW2; }
  int tl = tile - t0, ktI = tl/ntc, ntI = tl%ntc;
  int k = ktI*32 + ((lane>>4)<<3) + j, n = ntI*16 + (lane&15);
  float v = (k<K && n<N) ? src[k*N+n] : 0.f;
  ws[idx] = f2bf(v);
}

#define WV 4
__global__ __launch_bounds__(256) void k_token(P p, float* __restrict__ outp,
                                               const short* __restrict__ wsb) {
  __shared__ TS S[WV];
  __shared__ float h1[WV][128];
  __shared__ float h2[WV][128];
  const s16x8* wsv = (const s16x8*)wsb;
  int wid = threadIdx.x >> 6, l = threadIdx.x & 63;
  TS& s = S[wid];
  long tok = (long)blockIdx.x*WV + wid;
  int m = l & 15, q = l >> 4;
  int mm = m < 5 ? m : 4;
#define BFR(tile) wsv[(tile)*64 + l]

  const float* xr = p.x + (size_t)tok*DX;
  for (int i=l;i<DX;i+=64) s.xb[i] = xr[i];
  __syncthreads();

  // mask from r = nbr[...,0:3]
  if (l < SLOTS) { int nb = EGO_DD + l*PER;
    s.mk[l] = (fabsf(s.xb[nb])>1e-6f || fabsf(s.xb[nb+1])>1e-6f || fabsf(s.xb[nb+2])>1e-6f) ? 1 : 0; }
  __syncthreads();
  int nmask = s.mk[0]+s.mk[1]+s.mk[2]+s.mk[3]+s.mk[4];
  bool hasany = nmask>0;
  if (l < SLOTS) s.mks[l] = hasany ? s.mk[l] : (l==0 ? 1 : 0);

  // ---- ego/pair/ter (M=1) raw+bias -> zb[0:160]
  {
    s16x8 aE = packrow(&s.xb[q*8]);                 // K=32
    s16x8 aP = packrowb(&s.xb[107], q*8, 10);
    f32x4 e0={0,0,0,0},e1={0,0,0,0},e2={0,0,0,0},e3={0,0,0,0};
    e0=MFMA(aE,BFR(T_EGO+0),e0); e1=MFMA(aE,BFR(T_EGO+1),e1);
    e2=MFMA(aE,BFR(T_EGO+2),e2); e3=MFMA(aE,BFR(T_EGO+3),e3);
    f32x4 p0={0,0,0,0},p1={0,0,0,0};
    p0=MFMA(aP,BFR(T_PAIR+0),p0); p1=MFMA(aP,BFR(T_PAIR+1),p1);
    if (l<16){
      s.zb[l]    = e0[0]+p.b_ego[l];    s.zb[16+l] = e1[0]+p.b_ego[16+l];
      s.zb[32+l] = e2[0]+p.b_ego[32+l]; s.zb[48+l] = e3[0]+p.b_ego[48+l];
      s.zb[64+l] = p0[0]+p.b_pair[l];   s.zb[80+l] = p1[0]+p.b_pair[16+l];
    }
  }
  {
    f32x4 t0={0,0,0,0},t1={0,0,0,0},t2={0,0,0,0},t3={0,0,0,0};
    for(int kt=0;kt<3;kt++){
      s16x8 aT = packrowb(&s.xb[117], kt*32+q*8, 81);
      t0=MFMA(aT,BFR(T_TER+kt*4+0),t0); t1=MFMA(aT,BFR(T_TER+kt*4+1),t1);
      t2=MFMA(aT,BFR(T_TER+kt*4+2),t2); t3=MFMA(aT,BFR(T_TER+kt*4+3),t3);
    }
    if (l<16){
      s.zb[96+l] = t0[0]+p.b_ter[l];    s.zb[112+l]= t1[0]+p.b_ter[16+l];
      s.zb[128+l]= t2[0]+p.b_ter[32+l]; s.zb[144+l]= t3[0]+p.b_ter[48+l];
    }
  }
  // ---- invtok (M=16/5) raw+bias -> tv
  {
    int nb = EGO_DD + mm*PER;
    float a0=s.xb[nb+6],a1=s.xb[nb+7],a2v=s.xb[nb+8];
    float nrm = sqrtf(a0*a0+a1*a1+a2v*a2v);
    s16x8 af;
    #pragma unroll
    for(int j=0;j<8;j++){
      int k=q*8+j; float v;
      if(k<6) v=s.xb[nb+9+k];
      else if(k<9) v=s.xb[nb+k];
      else if(k==9) v=nrm;
      else v=0.f;
      af[j]=f2bf(v);
    }
    f32x4 c0={0,0,0,0},c1={0,0,0,0};
    c0=MFMA(af,BFR(T_INV+0),c0); c1=MFMA(af,BFR(T_INV+1),c1);
    #pragma unroll
    for(int r=0;r<4;r++){ int row=q*4+r;
      if(row<SLOTS){
        s.tv[row*ST+m]    = c0[r]+p.b_invtok[m];
        s.tv[row*ST+16+m] = c1[r]+p.b_invtok[16+m];
      }
    }
  }
  __syncthreads();
  // balanced gelu passes
  for(int i=l;i<160;i+=64){ float g=gelu_f(s.zb[i]); s.zb[i]=g; if(i<64) s.ego[i]=g; }
  for(int idx=l;idx<160;idx+=64){ int sl=idx>>5, ii=idx&31;
    float g = s.mk[sl] ? gelu_f(s.tv[sl*ST+ii]) : 0.f; s.tv[sl*ST+ii]=g; }
  __syncthreads();

  // ---- LN1 -> qkv
  ln5x32(s.tv, s.yb, p.ln1_s, p.ln1_b, l);
  __syncthreads();
  {
    s16x8 aY = packrow(&s.yb[mm*ST + q*8]);
    f32x4 q0={0,0,0,0},q1={0,0,0,0},k0v={0,0,0,0},k1v={0,0,0,0},v0={0,0,0,0},v1={0,0,0,0};
    q0=MFMA(aY,BFR(T_Q+0),q0);   q1=MFMA(aY,BFR(T_Q+1),q1);
    k0v=MFMA(aY,BFR(T_K+0),k0v); k1v=MFMA(aY,BFR(T_K+1),k1v);
    v0=MFMA(aY,BFR(T_V+0),v0);   v1=MFMA(aY,BFR(T_V+1),v1);
    #pragma unroll
    for(int r=0;r<4;r++){ int row=q*4+r;
      if(row<SLOTS){
        s.qb[row*ST+m]=q0[r]+p.bq[m];     s.qb[row*ST+16+m]=q1[r]+p.bq[16+m];
        s.kb[row*ST+m]=k0v[r]+p.bk[m];    s.kb[row*ST+16+m]=k1v[r]+p.bk[16+m];
        s.vb[row*ST+m]=v0[r]+p.bv[m];     s.vb[row*ST+16+m]=v1[r]+p.bv[16+m];
      }
    }
  }
  __syncthreads();
  // attention weights (20 lanes: h x q)
  if (l<20){
    int h=l/5, qs=l%5;
    float sc5[5]; float mx=NEGB;
    for(int ks=0;ks<5;ks++){
      float d8=0;
      for(int d=0;d<8;d++) d8 += s.qb[qs*ST+h*8+d]*s.kb[ks*ST+h*8+d];
      float v = (s.mks[qs]&&s.mks[ks]) ? d8*0.35355339059327373f : NEGB;
      sc5[ks]=v; mx=fmaxf(mx,v);
    }
    float se=0;
    for(int ks=0;ks<5;ks++){ float e=__expf(sc5[ks]-mx); sc5[ks]=e; se+=e; }
    float inv=1.f/se;
    for(int ks=0;ks<5;ks++) s.at[(h*5+qs)*5+ks]=sc5[ks]*inv;
  }
  __syncthreads();
  // attn @ v -> yb
  for (int idx=l; idx<160; idx+=64){
    int sl=idx>>5, i=idx&31, h=i>>3, d=i&7;
    float o=0;
    for(int ks=0;ks<5;ks++) o += s.at[(h*5+sl)*5+ks]*s.vb[ks*ST+h*8+d];
    s.yb[sl*ST+i]=o;
  }
  __syncthreads();
  // wo + residual (zero_masked)
  {
    s16x8 aY = packrow(&s.yb[mm*ST + q*8]);
    f32x4 c0={0,0,0,0},c1={0,0,0,0};
    c0=MFMA(aY,BFR(T_O+0),c0); c1=MFMA(aY,BFR(T_O+1),c1);
    #pragma unroll
    for(int r=0;r<4;r++){ int row=q*4+r;
      if(row<SLOTS && s.mk[row]){
        s.tv[row*ST+m]    += c0[r]+p.bo[m];
        s.tv[row*ST+16+m] += c1[r]+p.bo[16+m];
      }
    }
  }
  __syncthreads();
  // LN2 + FFN
  ln5x32(s.tv, s.yb, p.ln2_s, p.ln2_b, l);
  __syncthreads();
  {
    s16x8 aY = packrow(&s.yb[mm*ST + q*8]);
    f32x4 c0={0,0,0,0},c1={0,0,0,0},c2={0,0,0,0},c3={0,0,0,0};
    c0=MFMA(aY,BFR(T_W1+0),c0); c1=MFMA(aY,BFR(T_W1+1),c1);
    c2=MFMA(aY,BFR(T_W1+2),c2); c3=MFMA(aY,BFR(T_W1+3),c3);
    #pragma unroll
    for(int r=0;r<4;r++){ int row=q*4+r;
      if(row<SLOTS){
        s.hb[row*HBST+m]   =c0[r]+p.b1[m];
        s.hb[row*HBST+16+m]=c1[r]+p.b1[16+m];
        s.hb[row*HBST+32+m]=c2[r]+p.b1[32+m];
        s.hb[row*HBST+48+m]=c3[r]+p.b1[48+m];
      }
    }
  }
  __syncthreads();
  for(int idx=l;idx<320;idx+=64){ int sl=idx>>6,jj=idx&63;
    s.hb[sl*HBST+jj]=gelu_f(s.hb[sl*HBST+jj]); }
  __syncthreads();
  {
    f32x4 c0={0,0,0,0},c1={0,0,0,0};
    for(int kt=0;kt<2;kt++){
      s16x8 aH = packrow(&s.hb[mm*HBST + kt*32 + q*8]);
      c0=MFMA(aH,BFR(T_W2+kt*2+0),c0); c1=MFMA(aH,BFR(T_W2+kt*2+1),c1);
    }
    #pragma unroll
    for(int r=0;r<4;r++){ int row=q*4+r;
      if(row<SLOTS){
        float n0 = s.mk[row] ? s.tv[row*ST+m]+c0[r]+p.b2[m] : 0.f;
        float n1 = s.mk[row] ? s.tv[row*ST+16+m]+c1[r]+p.b2[16+m] : 0.f;
        s.tv[row*ST+m]=n0; s.tv[row*ST+16+m]=n1;
      }
    }
  }
  __syncthreads();

  // pools: mean / max ; sp LN
  if (l<32){
    float v0=s.tv[l],v1=s.tv[ST+l],v2=s.tv[2*ST+l],v3=s.tv[3*ST+l],v4=s.tv[4*ST+l];
    int cnt = nmask>0?nmask:1;
    s.zb[160+l]=(v0+v1+v2+v3+v4)/(float)cnt;
    float mx=-1e9f;
    if(s.mk[0])mx=fmaxf(mx,v0); if(s.mk[1])mx=fmaxf(mx,v1); if(s.mk[2])mx=fmaxf(mx,v2);
    if(s.mk[3])mx=fmaxf(mx,v3); if(s.mk[4])mx=fmaxf(mx,v4);
    s.zb[192+l]= hasany ? mx : 0.f;
  }
  ln5x32(s.tv, s.yb, p.sp_ln_s, p.sp_ln_b, l);
  __syncthreads();
  if (l<SLOTS){ float a=p.sp_b[0];
    for(int i=0;i<32;i++) a += s.yb[l*ST+i]*p.sp_w[i];
    s.scs[l]=a; }
  __syncthreads();
  if (l==0){
    float temp = log1pf(expf(p.sp_lt[0])) + 0.001f;
    msm5(s.scs, s.mk, s.wts, temp);
  }
  __syncthreads();
  if (l<32){ float a=0;
    for(int sl=0;sl<5;sl++) a += s.wts[sl]*s.tv[sl*ST+l];
    s.zb[224+l]=a; }
  // ap_wq (M=1, K=64) -> qeb
  {
    f32x4 c0={0,0,0,0},c1={0,0,0,0};
    for(int kt=0;kt<2;kt++){
      s16x8 aE = packrow(&s.ego[kt*32 + q*8]);
      c0=MFMA(aE,BFR(T_APQ+kt*2+0),c0); c1=MFMA(aE,BFR(T_APQ+kt*2+1),c1);
    }
    if(l<16){ s.qeb[l]=c0[0]+p.ap_bq[l]; s.qeb[16+l]=c1[0]+p.ap_bq[16+l]; }
  }
  __syncthreads();
  // ap_wk + qeb -> yb (raw)
  {
    s16x8 aT = packrow(&s.tv[mm*ST + q*8]);
    f32x4 c0={0,0,0,0},c1={0,0,0,0};
    c0=MFMA(aT,BFR(T_APK+0),c0); c1=MFMA(aT,BFR(T_APK+1),c1);
    #pragma unroll
    for(int r=0;r<4;r++){ int row=q*4+r;
      if(row<SLOTS){
        s.yb[row*ST+m]   =c0[r]+p.ap_bk[m]+s.qeb[m];
        s.yb[row*ST+16+m]=c1[r]+p.ap_bk[16+m]+s.qeb[16+m];
      }
    }
  }
  __syncthreads();
  for(int idx=l;idx<160;idx+=64){ int sl=idx>>5,ii=idx&31;
    s.yb[sl*ST+ii]=tanh_f(s.yb[sl*ST+ii]); }
  __syncthreads();
  if (l<SLOTS){ float a=p.ap_be[0];
    for(int i=0;i<32;i++) a += s.yb[l*ST+i]*p.ap_we[i];
    s.scs[l]=a; }
  __syncthreads();
  if (l==0) msm5(s.scs, s.mk, s.alp, 1.f);
  __syncthreads();
  if (l<32){ float a=0;
    for(int sl=0;sl<5;sl++) a += s.alp[sl]*s.tv[sl*ST+l];
    s.zb[256+l]=a; }
  // flat (M=1, K=160 over tv rows) -> zb[288:320) raw
  {
    f32x4 c0={0,0,0,0},c1={0,0,0,0};
    for(int kt=0;kt<5;kt++){
      s16x8 aF = packrow(&s.tv[kt*ST + q*8]);
      c0=MFMA(aF,BFR(T_FLAT+kt*2+0),c0); c1=MFMA(aF,BFR(T_FLAT+kt*2+1),c1);
    }
    if(l<16){ s.zb[288+l]=c0[0]+p.flat_b[l]; s.zb[304+l]=c1[0]+p.flat_b[16+l]; }
  }
  // vr_wego (M=1, K=64) -> egh
  {
    f32x4 c0={0,0,0,0},c1={0,0,0,0};
    for(int kt=0;kt<2;kt++){
      s16x8 aE = packrow(&s.ego[kt*32 + q*8]);
      c0=MFMA(aE,BFR(T_VEGO+kt*2+0),c0); c1=MFMA(aE,BFR(T_VEGO+kt*2+1),c1);
    }
    if(l<16){ s.egh[l]=c0[0]+p.vr_bego[l]; s.egh[16+l]=c1[0]+p.vr_bego[16+l]; }
  }
  __syncthreads();
  if(l<32) s.zb[288+l]=0.25f*gelu_f(s.zb[288+l]);
  ln5x32(s.tv, s.yb, p.vr_ln_s, p.vr_ln_b, l);
  __syncthreads();
  // vr_wh: A=[ln(t) | ego_h] -> qb raw
  {
    s16x8 aY = packrow(&s.yb[mm*ST + q*8]);
    s16x8 aE = packrow(&s.egh[q*8]);
    f32x4 c0={0,0,0,0},c1={0,0,0,0};
    c0=MFMA(aY,BFR(T_VH+0),c0); c1=MFMA(aY,BFR(T_VH+1),c1);
    c0=MFMA(aE,BFR(T_VH+2),c0); c1=MFMA(aE,BFR(T_VH+3),c1);
    #pragma unroll
    for(int r=0;r<4;r++){ int row=q*4+r;
      if(row<SLOTS){
        s.qb[row*ST+m]   =c0[r]+p.vr_bh[m];
        s.qb[row*ST+16+m]=c1[r]+p.vr_bh[16+m];
      }
    }
  }
  __syncthreads();
  for(int idx=l;idx<160;idx+=64){ int sl=idx>>5,ii=idx&31;
    s.qb[sl*ST+ii]=gelu_f(s.qb[sl*ST+ii]); }
  __syncthreads();
  if (l<10){ int sl=l>>1, hh=l&1;
    float a=p.vr_bl[hh];
    for(int i=0;i<32;i++) a += s.qb[sl*ST+i]*p.vr_wl[i*2+hh];
    s.lg[sl*2+hh]=a; }
  __syncthreads();
  if (l<2){ float tmp[5],o5[5];
    for(int sl=0;sl<5;sl++) tmp[sl]=s.lg[sl*2+l];
    msm5(tmp, s.mk, o5, 1.f);
    for(int sl=0;sl<5;sl++) s.a2[sl*2+l]=o5[sl]; }
  __syncthreads();
  if (l<12){ int w = l/6, rem=l%6, hh=rem/3, d=rem%3;
    float a=0;
    for(int sl=0;sl<5;sl++) a += s.a2[sl*2+hh]*s.xb[EGO_DD+sl*PER + w*3 + d];
    s.zb[320 + w*6 + hh*3 + d]=a; }
  __syncthreads();   // z[4][332] complete in LDS for all 4 waves

  // ---- fused z-phase (MFMA, validated round 4)
  {
    f32x4 acc0 = {0.f,0.f,0.f,0.f}, acc1 = {0.f,0.f,0.f,0.f};
    for (int kt=0; kt<11; kt++){
      s16x8 af;
      int k0 = kt*32 + q*8;
      if (m < 4){
        const float* zrow = S[m].zb;
        #pragma unroll
        for (int j=0;j<8;j++){ int kk=k0+j; af[j] = (kk<ZDIM) ? f2bf(zrow[kk]) : (short)0; }
      } else {
        #pragma unroll
        for (int j=0;j<8;j++) af[j]=0;
      }
      s16x8 b0 = wsv[(T_ZW1 + kt*8 + 2*wid  )*64 + l];
      s16x8 b1 = wsv[(T_ZW1 + kt*8 + 2*wid+1)*64 + l];
      acc0 = MFMA(af, b0, acc0);
      acc1 = MFMA(af, b1, acc1);
    }
    if (q == 0){
      int c0 = 2*wid*16 + m, c1 = (2*wid+1)*16 + m;
      float bb0 = p.z_b1[c0], bb1 = p.z_b1[c1];
      #pragma unroll
      for (int r=0;r<4;r++){
        h1[r][c0] = gelu_f(acc0[r] + bb0);
        h1[r][c1] = gelu_f(acc1[r] + bb1);
      }
    }
  }
  __syncthreads();
  {
    float v0 = h1[wid][l], v1 = h1[wid][l+64];
    float sum = v0+v1;
    for (int o=32;o>=1;o>>=1) sum += __shfl_xor(sum,o,64);
    float mu = sum*(1.f/128.f);
    float d0=v0-mu, d1=v1-mu;
    float qq = d0*d0+d1*d1;
    for (int o=32;o>=1;o>>=1) qq += __shfl_xor(qq,o,64);
    float rs = rsqrtf(qq*(1.f/128.f)+1e-6f);
    h1[wid][l]    = d0*rs*p.z_ln1_s[l]   +p.z_ln1_b[l];
    h1[wid][l+64] = d1*rs*p.z_ln1_s[l+64]+p.z_ln1_b[l+64];
  }
  __syncthreads();
  {
    f32x4 acc0 = {0.f,0.f,0.f,0.f}, acc1 = {0.f,0.f,0.f,0.f};
    for (int kt=0; kt<4; kt++){
      s16x8 af;
      int k0 = kt*32 + q*8;
      if (m < 4){
        const float* hrow = h1[m];
        #pragma unroll
        for (int j=0;j<8;j++) af[j] = f2bf(hrow[k0+j]);
      } else {
        #pragma unroll
        for (int j=0;j<8;j++) af[j]=0;
      }
      s16x8 b0 = wsv[(T_ZW2 + kt*8 + 2*wid  )*64 + l];
      s16x8 b1 = wsv[(T_ZW2 + kt*8 + 2*wid+1)*64 + l];
      acc0 = MFMA(af, b0, acc0);
      acc1 = MFMA(af, b1, acc1);
    }
    if (q == 0){
      int c0 = 2*wid*16 + m, c1 = (2*wid+1)*16 + m;
      float bb0 = p.z_b2[c0], bb1 = p.z_b2[c1];
      #pragma unroll
      for (int r=0;r<4;r++){
        h2[r][c0] = gelu_f(acc0[r] + bb0);
        h2[r][c1] = gelu_f(acc1[r] + bb1);
      }
    }
  }
  __syncthreads();
  // LN2 per wave + store
  {
    float v0 = h2[wid][l], v1 = h2[wid][l+64];
    float sum = v0+v1;
    for (int o=32;o>=1;o>>=1) sum += __shfl_xor(sum,o,64);
    float mu = sum*(1.f/128.f);
    float d0=v0-mu, d1=v1-mu;
    float qq = d0*d0+d1*d1;
    for (int o=32;o>=1;o>>=1) qq += __shfl_xor(qq,o,64);
    float rs = rsqrtf(qq*(1.f/128.f)+1e-6f);
    float o0 = d0*rs*p.z_ln2_s[l]   +p.z_ln2_b[l];
    float o1 = d1*rs*p.z_ln2_s[l+64]+p.z_ln2_b[l+64];
    float* op = outp + (size_t)tok*128;
    op[l]    = o0;
    op[l+64] = o1;
  }
}

extern "C" void kernel_launch(void* const* d_in, const int* in_sizes, int n_in,
                              void* d_out, int out_size, void* d_ws, size_t ws_size,
                              hipStream_t stream) {
  (void)in_sizes; (void)n_in; (void)out_size; (void)ws_size;
  P p;
  const void** pp = (const void**)&p;
  for (int i=0;i<54;i++) pp[i] = d_in[i];
  short* wsb = (short*)d_ws;   // 184320 B needed
  k_prep<<<(T_TOT*512+255)/256, 256, 0, stream>>>(p, wsb);
  k_token<<<NTOK/WV, 256, 0, stream>>>(p, (float*)d_out, wsb);
}

// Round 6
// 1504.019 us; speedup vs baseline: 1.9061x; 1.0563x over previous
//
#include <hip/hip_runtime.h>
#include <hip/hip_bf16.h>

#define SLOTS 5
#define PER 15
#define EGO_DD 32
#define PAIR_DD 10
#define TER_DD 81
#define DX 198
#define ZDIM 332
#define NTOK (64*2048)
#define NEGB (-3.402823466e38f)
#define ST 36      // padded stride for [5][32] slot arrays
#define HBST 68    // padded stride for [5][64] ffn hidden

// ---- B-fragment tile table ----
#define T_EGO   0
#define T_PAIR  4
#define T_TER   6
#define T_INV   18
#define T_Q     20
#define T_K     22
#define T_V     24
#define T_O     26
#define T_W1    28
#define T_W2    32
#define T_APQ   36
#define T_APK   40
#define T_FLAT  42
#define T_VEGO  52
#define T_VH    56
#define T_ZW1   60
#define T_ZW2   148
#define T_TOT   180
#define WS_NEED (T_TOT*512*2)

// ---- per-wave LDS pool layout (floats), PW = 1540 ----
// ego 0..64 | tv 64..244 | yb 244..424 | U 424..964 | at 964..1064 |
// zb 1064..1396 | qeb 1396..1428 | egh 1428..1460 | ru 1460..1492 | sm 1492..1540
// U overlays (disjoint lifetimes):
//   phase A: xb[200] @U+0
//   phase B: qb@U+0, kb@U+180, vb@U+360 (each 180)
//   phase C: hb[5*68=340] @U+0
//   phase D: vq[180] @U+0 (vr scratch)
//   phase E (z): h1[128]@U+0, h2[128]@U+128, zbh bf16[352]@U+300(176f), h1h bf16[128]@U+476(64f)
#define PW 1540
#define OF_EGO 0
#define OF_TV  64
#define OF_YB  244
#define OF_U   424
#define OF_AT  964
#define OF_ZB  1064
#define OF_QEB 1396
#define OF_EGH 1428
#define OF_RU  1460
#define OF_SM  1492

typedef float f32x4 __attribute__((ext_vector_type(4)));
typedef short s16x8 __attribute__((ext_vector_type(8)));
#define MFMA(a,b,c) __builtin_amdgcn_mfma_f32_16x16x32_bf16(a,b,c,0,0,0)

struct P {
  const float *x,*w_ego,*b_ego,*w_pair,*b_pair,*w_ter,*b_ter,*w_invtok,*b_invtok,
    *ln1_s,*ln1_b,*wq,*bq,*wk,*bk,*wv,*bv,*wo,*bo,*ln2_s,*ln2_b,*w1,*b1,*w2,*b2,
    *sp_ln_s,*sp_ln_b,*sp_w,*sp_b,*sp_lt,*ap_wq,*ap_bq,*ap_wk,*ap_bk,*ap_we,*ap_be,
    *flat_w,*flat_b,*vr_wego,*vr_bego,*vr_ln_s,*vr_ln_b,*vr_wh,*vr_bh,*vr_wl,*vr_bl,
    *z_w1,*z_b1,*z_ln1_s,*z_ln1_b,*z_w2,*z_b2,*z_ln2_s,*z_ln2_b;
};

__device__ __forceinline__ short f2bf(float x){
  __hip_bfloat16 h = __float2bfloat16(x);
  return *reinterpret_cast<short*>(&h);
}
__device__ __forceinline__ float tanh_f(float x){
  float e = __expf(2.f*x);
  return 1.f - 2.f/(e+1.f);
}
__device__ __forceinline__ float gelu_f(float x){
  return 0.5f*x*(1.f+tanh_f(0.7978845608028654f*(x + 0.044715f*x*x*x)));
}
__device__ __forceinline__ s16x8 packrow(const float* r){
  s16x8 af;
  #pragma unroll
  for(int j=0;j<8;j++) af[j]=f2bf(r[j]);
  return af;
}
__device__ __forceinline__ s16x8 packrowb(const float* r, int k0, int K){
  s16x8 af;
  #pragma unroll
  for(int j=0;j<8;j++) af[j] = (k0+j<K) ? f2bf(r[k0+j]) : (short)0;
  return af;
}

__device__ void msm5(const float* lgv, const int* m, float* outp, float scale){
  bool any = m[0]||m[1]||m[2]||m[3]||m[4];
  if(!any){ for(int s2=0;s2<5;s2++) outp[s2]=0.f; return; }
  float mx=NEGB;
  for(int s2=0;s2<5;s2++) if(m[s2]) mx=fmaxf(mx, scale*lgv[s2]);
  float e[5], se=0.f;
  for(int s2=0;s2<5;s2++){ e[s2]= m[s2]? __expf(scale*lgv[s2]-mx):0.f; se+=e[s2]; }
  float inv=1.f/se;
  for(int s2=0;s2<5;s2++) outp[s2]=e[s2]*inv;
}

// LayerNorm over 5 rows of 32 (stride ST)
__device__ void ln5x32(const float* src, float* dst, const float* Sc, const float* Bi, int l){
  for (int sp=0; sp<6; sp+=2){
    int sl = sp + (l>>5), i = l&31;
    bool act = sl < SLOTS;
    float v = act ? src[sl*ST+i] : 0.f;
    float sum=v;
    sum+=__shfl_xor(sum,16,32); sum+=__shfl_xor(sum,8,32); sum+=__shfl_xor(sum,4,32);
    sum+=__shfl_xor(sum,2,32);  sum+=__shfl_xor(sum,1,32);
    float mu=sum*(1.f/32.f);
    float d = v-mu;
    float q=d*d;
    q+=__shfl_xor(q,16,32); q+=__shfl_xor(q,8,32); q+=__shfl_xor(q,4,32);
    q+=__shfl_xor(q,2,32);  q+=__shfl_xor(q,1,32);
    float rstd=rsqrtf(q*(1.f/32.f)+1e-6f);
    if(act) dst[sl*ST+i]=d*rstd*Sc[i]+Bi[i];
  }
}

// pack all weights into bf16 B-fragments
__global__ __launch_bounds__(256) void k_prep(P p, short* __restrict__ ws){
  int idx = blockIdx.x*256 + threadIdx.x;
  if (idx >= T_TOT*512) return;
  int j = idx & 7, lane = (idx>>3)&63, tile = idx>>9;
  const float* src; int K,N,ntc,t0;
  if      (tile < T_PAIR){ src=p.w_ego;   K=32;  N=64;  ntc=4; t0=T_EGO; }
  else if (tile < T_TER ){ src=p.w_pair;  K=10;  N=32;  ntc=2; t0=T_PAIR; }
  else if (tile < T_INV ){ src=p.w_ter;   K=81;  N=64;  ntc=4; t0=T_TER; }
  else if (tile < T_Q   ){ src=p.w_invtok;K=10;  N=32;  ntc=2; t0=T_INV; }
  else if (tile < T_K   ){ src=p.wq;      K=32;  N=32;  ntc=2; t0=T_Q; }
  else if (tile < T_V   ){ src=p.wk;      K=32;  N=32;  ntc=2; t0=T_K; }
  else if (tile < T_O   ){ src=p.wv;      K=32;  N=32;  ntc=2; t0=T_V; }
  else if (tile < T_W1  ){ src=p.wo;      K=32;  N=32;  ntc=2; t0=T_O; }
  else if (tile < T_W2  ){ src=p.w1;      K=32;  N=64;  ntc=4; t0=T_W1; }
  else if (tile < T_APQ ){ src=p.w2;      K=64;  N=32;  ntc=2; t0=T_W2; }
  else if (tile < T_APK ){ src=p.ap_wq;   K=64;  N=32;  ntc=2; t0=T_APQ; }
  else if (tile < T_FLAT){ src=p.ap_wk;   K=32;  N=32;  ntc=2; t0=T_APK; }
  else if (tile < T_VEGO){ src=p.flat_w;  K=160; N=32;  ntc=2; t0=T_FLAT; }
  else if (tile < T_VH  ){ src=p.vr_wego; K=64;  N=32;  ntc=2; t0=T_VEGO; }
  else if (tile < T_ZW1 ){ src=p.vr_wh;   K=64;  N=32;  ntc=2; t0=T_VH; }
  else if (tile < T_ZW2 ){ src=p.z_w1;    K=ZDIM;N=128; ntc=8; t0=T_ZW1; }
  else                   { src=p.z_w2;    K=128; N=128; ntc=8; t0=T_ZW2; }
  int tl = tile - t0, ktI = tl/ntc, ntI = tl%ntc;
  int k = ktI*32 + ((lane>>4)<<3) + j, n = ntI*16 + (lane&15);
  float v = (k<K && n<N) ? src[k*N+n] : 0.f;
  ws[idx] = f2bf(v);
}

#define WV 4
__global__ __launch_bounds__(256) void k_token(P p, float* __restrict__ outp,
                                               const short* __restrict__ wsb) {
  __shared__ __align__(16) float pool[WV*PW];
  __shared__ int mkA[WV][5];
  __shared__ int mksA[WV][5];
  const s16x8* wsv = (const s16x8*)wsb;
  int wid = threadIdx.x >> 6, l = threadIdx.x & 63;
  float* W   = pool + wid*PW;
  float* ego = W + OF_EGO;
  float* tv  = W + OF_TV;
  float* yb  = W + OF_YB;
  float* U   = W + OF_U;
  float* at  = W + OF_AT;
  float* zb  = W + OF_ZB;
  float* qeb = W + OF_QEB;
  float* egh = W + OF_EGH;
  float* ru  = W + OF_RU;
  float* sm  = W + OF_SM;
  float* scs = sm+0; float* wts = sm+5; float* alp = sm+10; float* lg = sm+16; float* a2 = sm+26;
  int* mk  = mkA[wid];
  int* mks = mksA[wid];
  // U overlays
  float* xb = U;                // phase A
  float* qb = U;  float* kb = U+180;  float* vb = U+360;   // phase B
  float* hb = U;                // phase C
  float* vq = U;                // phase D
  long tok = (long)blockIdx.x*WV + wid;
  int m = l & 15, q = l >> 4;
  int mm = m < 5 ? m : 4;
#define BFR(tile) wsv[(tile)*64 + l]

  const float* xr = p.x + (size_t)tok*DX;
  for (int i=l;i<DX;i+=64) xb[i] = xr[i];
  __syncthreads();

  // mask from r = nbr[...,0:3]
  if (l < SLOTS) { int nb = EGO_DD + l*PER;
    mk[l] = (fabsf(xb[nb])>1e-6f || fabsf(xb[nb+1])>1e-6f || fabsf(xb[nb+2])>1e-6f) ? 1 : 0; }
  // save r/u for final z-tail (xb will be overwritten)
  if (l < 30){ int sl=l/6, d=l%6; ru[l] = xb[EGO_DD + sl*PER + d]; }
  __syncthreads();
  int nmask = mk[0]+mk[1]+mk[2]+mk[3]+mk[4];
  bool hasany = nmask>0;
  if (l < SLOTS) mks[l] = hasany ? mk[l] : (l==0 ? 1 : 0);

  // ---- ego/pair/ter (M=1) raw+bias -> zb[0:160]
  {
    s16x8 aE = packrow(&xb[q*8]);
    s16x8 aP = packrowb(&xb[107], q*8, 10);
    f32x4 e0={0,0,0,0},e1={0,0,0,0},e2={0,0,0,0},e3={0,0,0,0};
    e0=MFMA(aE,BFR(T_EGO+0),e0); e1=MFMA(aE,BFR(T_EGO+1),e1);
    e2=MFMA(aE,BFR(T_EGO+2),e2); e3=MFMA(aE,BFR(T_EGO+3),e3);
    f32x4 p0={0,0,0,0},p1={0,0,0,0};
    p0=MFMA(aP,BFR(T_PAIR+0),p0); p1=MFMA(aP,BFR(T_PAIR+1),p1);
    if (l<16){
      zb[l]    = e0[0]+p.b_ego[l];    zb[16+l] = e1[0]+p.b_ego[16+l];
      zb[32+l] = e2[0]+p.b_ego[32+l]; zb[48+l] = e3[0]+p.b_ego[48+l];
      zb[64+l] = p0[0]+p.b_pair[l];   zb[80+l] = p1[0]+p.b_pair[16+l];
    }
  }
  {
    f32x4 t0={0,0,0,0},t1={0,0,0,0},t2={0,0,0,0},t3={0,0,0,0};
    for(int kt=0;kt<3;kt++){
      s16x8 aT = packrowb(&xb[117], kt*32+q*8, 81);
      t0=MFMA(aT,BFR(T_TER+kt*4+0),t0); t1=MFMA(aT,BFR(T_TER+kt*4+1),t1);
      t2=MFMA(aT,BFR(T_TER+kt*4+2),t2); t3=MFMA(aT,BFR(T_TER+kt*4+3),t3);
    }
    if (l<16){
      zb[96+l] = t0[0]+p.b_ter[l];    zb[112+l]= t1[0]+p.b_ter[16+l];
      zb[128+l]= t2[0]+p.b_ter[32+l]; zb[144+l]= t3[0]+p.b_ter[48+l];
    }
  }
  // ---- invtok (M=16/5) raw+bias -> tv
  {
    int nb = EGO_DD + mm*PER;
    float a0=xb[nb+6],a1=xb[nb+7],a2v=xb[nb+8];
    float nrm = sqrtf(a0*a0+a1*a1+a2v*a2v);
    s16x8 af;
    #pragma unroll
    for(int j=0;j<8;j++){
      int k=q*8+j; float v;
      if(k<6) v=xb[nb+9+k];
      else if(k<9) v=xb[nb+k];
      else if(k==9) v=nrm;
      else v=0.f;
      af[j]=f2bf(v);
    }
    f32x4 c0={0,0,0,0},c1={0,0,0,0};
    c0=MFMA(af,BFR(T_INV+0),c0); c1=MFMA(af,BFR(T_INV+1),c1);
    #pragma unroll
    for(int r=0;r<4;r++){ int row=q*4+r;
      if(row<SLOTS){
        tv[row*ST+m]    = c0[r]+p.b_invtok[m];
        tv[row*ST+16+m] = c1[r]+p.b_invtok[16+m];
      }
    }
  }
  __syncthreads();
  for(int i=l;i<160;i+=64){ float g=gelu_f(zb[i]); zb[i]=g; if(i<64) ego[i]=g; }
  for(int idx=l;idx<160;idx+=64){ int sl=idx>>5, ii=idx&31;
    float g = mk[sl] ? gelu_f(tv[sl*ST+ii]) : 0.f; tv[sl*ST+ii]=g; }
  __syncthreads();   // xb dead from here; U becomes qb/kb/vb

  // ---- LN1 -> qkv
  ln5x32(tv, yb, p.ln1_s, p.ln1_b, l);
  __syncthreads();
  {
    s16x8 aY = packrow(&yb[mm*ST + q*8]);
    f32x4 q0={0,0,0,0},q1={0,0,0,0},k0v={0,0,0,0},k1v={0,0,0,0},v0={0,0,0,0},v1={0,0,0,0};
    q0=MFMA(aY,BFR(T_Q+0),q0);   q1=MFMA(aY,BFR(T_Q+1),q1);
    k0v=MFMA(aY,BFR(T_K+0),k0v); k1v=MFMA(aY,BFR(T_K+1),k1v);
    v0=MFMA(aY,BFR(T_V+0),v0);   v1=MFMA(aY,BFR(T_V+1),v1);
    #pragma unroll
    for(int r=0;r<4;r++){ int row=q*4+r;
      if(row<SLOTS){
        qb[row*ST+m]=q0[r]+p.bq[m];     qb[row*ST+16+m]=q1[r]+p.bq[16+m];
        kb[row*ST+m]=k0v[r]+p.bk[m];    kb[row*ST+16+m]=k1v[r]+p.bk[16+m];
        vb[row*ST+m]=v0[r]+p.bv[m];     vb[row*ST+16+m]=v1[r]+p.bv[16+m];
      }
    }
  }
  __syncthreads();
  // attention weights (20 lanes: h x q)
  if (l<20){
    int h=l/5, qs=l%5;
    float sc5[5]; float mx=NEGB;
    for(int ks=0;ks<5;ks++){
      float d8=0;
      for(int d=0;d<8;d++) d8 += qb[qs*ST+h*8+d]*kb[ks*ST+h*8+d];
      float v = (mks[qs]&&mks[ks]) ? d8*0.35355339059327373f : NEGB;
      sc5[ks]=v; mx=fmaxf(mx,v);
    }
    float se=0;
    for(int ks=0;ks<5;ks++){ float e=__expf(sc5[ks]-mx); sc5[ks]=e; se+=e; }
    float inv=1.f/se;
    for(int ks=0;ks<5;ks++) at[(h*5+qs)*5+ks]=sc5[ks]*inv;
  }
  __syncthreads();
  // attn @ v -> yb
  for (int idx=l; idx<160; idx+=64){
    int sl=idx>>5, i=idx&31, h=i>>3, d=i&7;
    float o=0;
    for(int ks=0;ks<5;ks++) o += at[(h*5+sl)*5+ks]*vb[ks*ST+h*8+d];
    yb[sl*ST+i]=o;
  }
  __syncthreads();
  // wo + residual (zero_masked)
  {
    s16x8 aY = packrow(&yb[mm*ST + q*8]);
    f32x4 c0={0,0,0,0},c1={0,0,0,0};
    c0=MFMA(aY,BFR(T_O+0),c0); c1=MFMA(aY,BFR(T_O+1),c1);
    #pragma unroll
    for(int r=0;r<4;r++){ int row=q*4+r;
      if(row<SLOTS && mk[row]){
        tv[row*ST+m]    += c0[r]+p.bo[m];
        tv[row*ST+16+m] += c1[r]+p.bo[16+m];
      }
    }
  }
  __syncthreads();
  // LN2 + FFN (qb/kb/vb dead; U becomes hb)
  ln5x32(tv, yb, p.ln2_s, p.ln2_b, l);
  __syncthreads();
  {
    s16x8 aY = packrow(&yb[mm*ST + q*8]);
    f32x4 c0={0,0,0,0},c1={0,0,0,0},c2={0,0,0,0},c3={0,0,0,0};
    c0=MFMA(aY,BFR(T_W1+0),c0); c1=MFMA(aY,BFR(T_W1+1),c1);
    c2=MFMA(aY,BFR(T_W1+2),c2); c3=MFMA(aY,BFR(T_W1+3),c3);
    #pragma unroll
    for(int r=0;r<4;r++){ int row=q*4+r;
      if(row<SLOTS){
        hb[row*HBST+m]   =c0[r]+p.b1[m];
        hb[row*HBST+16+m]=c1[r]+p.b1[16+m];
        hb[row*HBST+32+m]=c2[r]+p.b1[32+m];
        hb[row*HBST+48+m]=c3[r]+p.b1[48+m];
      }
    }
  }
  __syncthreads();
  for(int idx=l;idx<320;idx+=64){ int sl=idx>>6,jj=idx&63;
    hb[sl*HBST+jj]=gelu_f(hb[sl*HBST+jj]); }
  __syncthreads();
  {
    f32x4 c0={0,0,0,0},c1={0,0,0,0};
    for(int kt=0;kt<2;kt++){
      s16x8 aH = packrow(&hb[mm*HBST + kt*32 + q*8]);
      c0=MFMA(aH,BFR(T_W2+kt*2+0),c0); c1=MFMA(aH,BFR(T_W2+kt*2+1),c1);
    }
    #pragma unroll
    for(int r=0;r<4;r++){ int row=q*4+r;
      if(row<SLOTS){
        float n0 = mk[row] ? tv[row*ST+m]+c0[r]+p.b2[m] : 0.f;
        float n1 = mk[row] ? tv[row*ST+16+m]+c1[r]+p.b2[16+m] : 0.f;
        tv[row*ST+m]=n0; tv[row*ST+16+m]=n1;
      }
    }
  }
  __syncthreads();

  // pools: mean / max
  if (l<32){
    float v0=tv[l],v1=tv[ST+l],v2=tv[2*ST+l],v3=tv[3*ST+l],v4=tv[4*ST+l];
    int cnt = nmask>0?nmask:1;
    zb[160+l]=(v0+v1+v2+v3+v4)/(float)cnt;
    float mx=-1e9f;
    if(mk[0])mx=fmaxf(mx,v0); if(mk[1])mx=fmaxf(mx,v1); if(mk[2])mx=fmaxf(mx,v2);
    if(mk[3])mx=fmaxf(mx,v3); if(mk[4])mx=fmaxf(mx,v4);
    zb[192+l]= hasany ? mx : 0.f;
  }
  ln5x32(tv, yb, p.sp_ln_s, p.sp_ln_b, l);
  __syncthreads();
  if (l<SLOTS){ float a=p.sp_b[0];
    for(int i=0;i<32;i++) a += yb[l*ST+i]*p.sp_w[i];
    scs[l]=a; }
  __syncthreads();
  if (l==0){
    float temp = log1pf(expf(p.sp_lt[0])) + 0.001f;
    msm5(scs, mk, wts, temp);
  }
  __syncthreads();
  if (l<32){ float a=0;
    for(int sl=0;sl<5;sl++) a += wts[sl]*tv[sl*ST+l];
    zb[224+l]=a; }
  // ap_wq (M=1, K=64) -> qeb
  {
    f32x4 c0={0,0,0,0},c1={0,0,0,0};
    for(int kt=0;kt<2;kt++){
      s16x8 aE = packrow(&ego[kt*32 + q*8]);
      c0=MFMA(aE,BFR(T_APQ+kt*2+0),c0); c1=MFMA(aE,BFR(T_APQ+kt*2+1),c1);
    }
    if(l<16){ qeb[l]=c0[0]+p.ap_bq[l]; qeb[16+l]=c1[0]+p.ap_bq[16+l]; }
  }
  __syncthreads();
  // ap_wk + qeb -> yb (raw)
  {
    s16x8 aT = packrow(&tv[mm*ST + q*8]);
    f32x4 c0={0,0,0,0},c1={0,0,0,0};
    c0=MFMA(aT,BFR(T_APK+0),c0); c1=MFMA(aT,BFR(T_APK+1),c1);
    #pragma unroll
    for(int r=0;r<4;r++){ int row=q*4+r;
      if(row<SLOTS){
        yb[row*ST+m]   =c0[r]+p.ap_bk[m]+qeb[m];
        yb[row*ST+16+m]=c1[r]+p.ap_bk[16+m]+qeb[16+m];
      }
    }
  }
  __syncthreads();
  for(int idx=l;idx<160;idx+=64){ int sl=idx>>5,ii=idx&31;
    yb[sl*ST+ii]=tanh_f(yb[sl*ST+ii]); }
  __syncthreads();
  if (l<SLOTS){ float a=p.ap_be[0];
    for(int i=0;i<32;i++) a += yb[l*ST+i]*p.ap_we[i];
    scs[l]=a; }
  __syncthreads();
  if (l==0) msm5(scs, mk, alp, 1.f);
  __syncthreads();
  if (l<32){ float a=0;
    for(int sl=0;sl<5;sl++) a += alp[sl]*tv[sl*ST+l];
    zb[256+l]=a; }
  // flat (M=1, K=160 over tv rows) -> zb[288:320) raw
  {
    f32x4 c0={0,0,0,0},c1={0,0,0,0};
    for(int kt=0;kt<5;kt++){
      s16x8 aF = packrow(&tv[kt*ST + q*8]);
      c0=MFMA(aF,BFR(T_FLAT+kt*2+0),c0); c1=MFMA(aF,BFR(T_FLAT+kt*2+1),c1);
    }
    if(l<16){ zb[288+l]=c0[0]+p.flat_b[l]; zb[304+l]=c1[0]+p.flat_b[16+l]; }
  }
  // vr_wego (M=1, K=64) -> egh
  {
    f32x4 c0={0,0,0,0},c1={0,0,0,0};
    for(int kt=0;kt<2;kt++){
      s16x8 aE = packrow(&ego[kt*32 + q*8]);
      c0=MFMA(aE,BFR(T_VEGO+kt*2+0),c0); c1=MFMA(aE,BFR(T_VEGO+kt*2+1),c1);
    }
    if(l<16){ egh[l]=c0[0]+p.vr_bego[l]; egh[16+l]=c1[0]+p.vr_bego[16+l]; }
  }
  __syncthreads();
  if(l<32) zb[288+l]=0.25f*gelu_f(zb[288+l]);
  ln5x32(tv, yb, p.vr_ln_s, p.vr_ln_b, l);
  __syncthreads();   // hb dead; U becomes vq
  // vr_wh: A=[ln(t) | ego_h] -> vq raw
  {
    s16x8 aY = packrow(&yb[mm*ST + q*8]);
    s16x8 aE = packrow(&egh[q*8]);
    f32x4 c0={0,0,0,0},c1={0,0,0,0};
    c0=MFMA(aY,BFR(T_VH+0),c0); c1=MFMA(aY,BFR(T_VH+1),c1);
    c0=MFMA(aE,BFR(T_VH+2),c0); c1=MFMA(aE,BFR(T_VH+3),c1);
    #pragma unroll
    for(int r=0;r<4;r++){ int row=q*4+r;
      if(row<SLOTS){
        vq[row*ST+m]   =c0[r]+p.vr_bh[m];
        vq[row*ST+16+m]=c1[r]+p.vr_bh[16+m];
      }
    }
  }
  __syncthreads();
  for(int idx=l;idx<160;idx+=64){ int sl=idx>>5,ii=idx&31;
    vq[sl*ST+ii]=gelu_f(vq[sl*ST+ii]); }
  __syncthreads();
  if (l<10){ int sl=l>>1, hh=l&1;
    float a=p.vr_bl[hh];
    for(int i=0;i<32;i++) a += vq[sl*ST+i]*p.vr_wl[i*2+hh];
    lg[sl*2+hh]=a; }
  __syncthreads();
  if (l<2){ float tmp[5],o5[5];
    for(int sl=0;sl<5;sl++) tmp[sl]=lg[sl*2+l];
    msm5(tmp, mk, o5, 1.f);
    for(int sl=0;sl<5;sl++) a2[sl*2+l]=o5[sl]; }
  __syncthreads();
  if (l<12){ int w = l/6, rem=l%6, hh=rem/3, d=rem%3;
    float a=0;
    for(int sl=0;sl<5;sl++) a += a2[sl*2+hh]*ru[sl*6 + w*3 + d];
    zb[320 + w*6 + hh*3 + d]=a; }
  __syncthreads();   // z[4][332] complete; vq dead; U becomes z-phase overlay

  // convert own zb -> bf16 zbh (352 entries, >=ZDIM zeroed)
  {
    short* zbh = (short*)(W + OF_U + 300);
    for (int i=l;i<352;i+=64) zbh[i] = (i<ZDIM) ? f2bf(zb[i]) : (short)0;
  }
  __syncthreads();

  // ---- fused z-phase (MFMA): GEMM1 K=352
  {
    f32x4 acc0 = {0.f,0.f,0.f,0.f}, acc1 = {0.f,0.f,0.f,0.f};
    const short* zbhM = (const short*)(pool + (m<4?m:0)*PW + OF_U + 300);
    for (int kt=0; kt<11; kt++){
      s16x8 af;
      if (m < 4) af = *(const s16x8*)&zbhM[kt*32 + q*8];
      else {ated: ;
        #pragma unroll
        for (int j=0;j<8;j++) af[j]=0;
      }
      s16x8 b0 = wsv[(T_ZW1 + kt*8 + 2*wid  )*64 + l];
      s16x8 b1 = wsv[(T_ZW1 + kt*8 + 2*wid+1)*64 + l];
      acc0 = MFMA(af, b0, acc0);
      acc1 = MFMA(af, b1, acc1);
    }
    if (q == 0){
      int c0 = 2*wid*16 + m, c1 = (2*wid+1)*16 + m;
      float bb0 = p.z_b1[c0], bb1 = p.z_b1[c1];
      #pragma unroll
      for (int r=0;r<4;r++){
        pool[r*PW + OF_U + c0] = gelu_f(acc0[r] + bb0);   // h1
        pool[r*PW + OF_U + c1] = gelu_f(acc1[r] + bb1);
      }
    }
  }
  __syncthreads();
  // LN1 on own token's h1 -> h1h (bf16)
  {
    float v0 = pool[wid*PW + OF_U + l], v1 = pool[wid*PW + OF_U + l+64];
    float sum = v0+v1;
    for (int o=32;o>=1;o>>=1) sum += __shfl_xor(sum,o,64);
    float mu = sum*(1.f/128.f);
    float d0=v0-mu, d1=v1-mu;
    float qq = d0*d0+d1*d1;
    for (int o=32;o>=1;o>>=1) qq += __shfl_xor(qq,o,64);
    float rs = rsqrtf(qq*(1.f/128.f)+1e-6f);
    short* h1h = (short*)(W + OF_U + 476);
    h1h[l]    = f2bf(d0*rs*p.z_ln1_s[l]   +p.z_ln1_b[l]);
    h1h[l+64] = f2bf(d1*rs*p.z_ln1_s[l+64]+p.z_ln1_b[l+64]);
  }
  __syncthreads();
  // GEMM2 K=128
  {
    f32x4 acc0 = {0.f,0.f,0.f,0.f}, acc1 = {0.f,0.f,0.f,0.f};
    const short* h1hM = (const short*)(pool + (m<4?m:0)*PW + OF_U + 476);
    for (int kt=0; kt<4; kt++){
      s16x8 af;
      if (m < 4) af = *(const s16x8*)&h1hM[kt*32 + q*8];
      else {
        #pragma unroll
        for (int j=0;j<8;j++) af[j]=0;
      }
      s16x8 b0 = wsv[(T_ZW2 + kt*8 + 2*wid  )*64 + l];
      s16x8 b1 = wsv[(T_ZW2 + kt*8 + 2*wid+1)*64 + l];
      acc0 = MFMA(af, b0, acc0);
      acc1 = MFMA(af, b1, acc1);
    }
    if (q == 0){
      int c0 = 2*wid*16 + m, c1 = (2*wid+1)*16 + m;
      float bb0 = p.z_b2[c0], bb1 = p.z_b2[c1];
      #pragma unroll
      for (int r=0;r<4;r++){
        pool[r*PW + OF_U + 128 + c0] = gelu_f(acc0[r] + bb0);   // h2
        pool[r*PW + OF_U + 128 + c1] = gelu_f(acc1[r] + bb1);
      }
    }
  }
  __syncthreads();
  // LN2 per wave + store
  {
    float v0 = pool[wid*PW + OF_U + 128 + l], v1 = pool[wid*PW + OF_U + 128 + l+64];
    float sum = v0+v1;
    for (int o=32;o>=1;o>>=1) sum += __shfl_xor(sum,o,64);
    float mu = sum*(1.f/128.f);
    float d0=v0-mu, d1=v1-mu;
    float qq = d0*d0+d1*d1;
    for (int o=32;o>=1;o>>=1) qq += __shfl_xor(qq,o,64);
    float rs = rsqrtf(qq*(1.f/128.f)+1e-6f);
    float o0 = d0*rs*p.z_ln2_s[l]   +p.z_ln2_b[l];
    float o1 = d1*rs*p.z_ln2_s[l+64]+p.z_ln2_b[l+64];
    float* op = outp + (size_t)tok*128;
    op[l]    = o0;
    op[l+64] = o1;
  }
}

extern "C" void kernel_launch(void* const* d_in, const int* in_sizes, int n_in,
                              void* d_out, int out_size, void* d_ws, size_t ws_size,
                              hipStream_t stream) {
  (void)in_sizes; (void)n_in; (void)out_size; (void)ws_size;
  P p;
  const void** pp = (const void**)&p;
  for (int i=0;i<54;i++) pp[i] = d_in[i];
  short* wsb = (short*)d_ws;   // 184320 B needed
  k_prep<<<(T_TOT*512+255)/256, 256, 0, stream>>>(p, wsb);
  k_token<<<NTOK/WV, 256, 0, stream>>>(p, (float*)d_out, wsb);
}